// Round 11
// baseline (1161.850 us; speedup 1.0000x reference)
//
#include <hip/hip_runtime.h>

// Problem constants (from reference)
constexpr int N  = 50000;
constexpr int E  = 300000;
constexpr int B  = 8;
constexpr int XD = 160;
constexpr int ED = 16;
constexpr int H  = 256;
constexpr int L  = 4;
constexpr int G  = 32;

typedef __attribute__((ext_vector_type(8))) short short8;
typedef __attribute__((ext_vector_type(4))) short sv4;
typedef __attribute__((ext_vector_type(4))) float floatx4;

// f32 -> bf16 round-to-nearest-even
__device__ __forceinline__ short f2bf(float f) {
    union { float f; unsigned u; } v; v.f = f;
    unsigned r = (v.u + 0x7fffu + ((v.u >> 16) & 1u)) >> 16;
    return (short)r;
}
__device__ __forceinline__ float bf2f(short s) {
    union { unsigned u; float f; } v;
    v.u = ((unsigned)(unsigned short)s) << 16;
    return v.f;
}

// ---------------------------------------------------------------------------
// CSR build: histogram, 3-pass multi-block scan, fill (+ edge-attr reorder)
// ---------------------------------------------------------------------------
__global__ __launch_bounds__(256) void hist_kernel(
    const int* __restrict__ dst, int* __restrict__ cnt)
{
    int e = blockIdx.x * 256 + threadIdx.x;
    if (e < E) atomicAdd(&cnt[dst[e]], 1);
}

__global__ __launch_bounds__(256) void scan_partial_kernel(
    const int* __restrict__ cnt, int* __restrict__ bsum)
{
    __shared__ int s[256];
    const int tid = threadIdx.x;
    int i = blockIdx.x * 256 + tid;
    s[tid] = (i < N) ? cnt[i] : 0;
    __syncthreads();
    #pragma unroll
    for (int off = 128; off > 0; off >>= 1) {
        if (tid < off) s[tid] += s[tid + off];
        __syncthreads();
    }
    if (tid == 0) bsum[blockIdx.x] = s[0];
}

__global__ __launch_bounds__(256) void scan_bsum_kernel(
    int* __restrict__ bsum, int nb, int* __restrict__ rsN)
{
    __shared__ int s[256];
    const int tid = threadIdx.x;
    int v = (tid < nb) ? bsum[tid] : 0;
    s[tid] = v;
    __syncthreads();
    #pragma unroll
    for (int off = 1; off < 256; off <<= 1) {
        int x = (tid >= off) ? s[tid - off] : 0;
        __syncthreads();
        s[tid] += x;
        __syncthreads();
    }
    if (tid < nb) bsum[tid] = s[tid] - v;
    if (tid == 255) *rsN = s[255];
}

__global__ __launch_bounds__(256) void scan_final_kernel(
    const int* __restrict__ cnt, const int* __restrict__ bsum,
    int* __restrict__ rs, int* __restrict__ cursor)
{
    __shared__ int s[256];
    const int tid = threadIdx.x;
    int i = blockIdx.x * 256 + tid;
    int v = (i < N) ? cnt[i] : 0;
    s[tid] = v;
    __syncthreads();
    #pragma unroll
    for (int off = 1; off < 256; off <<= 1) {
        int x = (tid >= off) ? s[tid - off] : 0;
        __syncthreads();
        s[tid] += x;
        __syncthreads();
    }
    int excl = s[tid] - v + bsum[blockIdx.x];
    if (i < N) { rs[i] = excl; cursor[i] = excl; }
}

// fill + CSR-reorder of edge attrs: ea_csr[pos] = ea[e].
__global__ __launch_bounds__(256) void fill_kernel(
    const int* __restrict__ src, const int* __restrict__ dst,
    const float* __restrict__ ea,
    int* __restrict__ cursor, int* __restrict__ csr_src,
    float* __restrict__ ea_csr)
{
    int e = blockIdx.x * 256 + threadIdx.x;
    if (e < E) {
        int d = dst[e];
        int pos = atomicAdd(&cursor[d], 1);
        csr_src[pos] = src[e];
        const float4* a = (const float4*)(ea + (size_t)e * ED);
        float4* o = (float4*)(ea_csr + (size_t)pos * ED);
        o[0] = a[0]; o[1] = a[1]; o[2] = a[2]; o[3] = a[3];
    }
}

// ---------------------------------------------------------------------------
// hiddenAgg via MFMA: per block, 32 nodes; loop 64-edge windows of the
// CSR-contiguous edge range.
//   GEMM1: R = relu(EA @ W + b)           (edges x 256, K=32 zero-padded)
//   GEMM2: hagg += S @ R                   (nodes x 256, K=64)
// ---------------------------------------------------------------------------
__global__ __launch_bounds__(256, 3) void hidden_agg_mfma_kernel(
    const float* __restrict__ ea_csr,
    const short* __restrict__ ew1T, const float* __restrict__ eb1,
    const int* __restrict__ rs,
    short* __restrict__ haggB)
{
    __shared__ short EA[64 * 32];      // [edge][k] bf16, k 16..31 zero
    __shared__ short RT[256 * 68];     // [col][edge] bf16
    __shared__ short S [32 * 68];      // [node][edge] bf16 0/1
    __shared__ int rsL[33];
    const int tid  = threadIdx.x;
    const int lane = tid & 63, wave = tid >> 6;
    const int quad = lane >> 4, lm = lane & 15;
    const int n0 = blockIdx.x * 32;
    const int nvalid = min(32, N - n0);
    const int ncol = wave * 64 + lm;

    if (tid < 33) rsL[tid] = rs[min(n0 + tid, N)];
    for (int i = tid; i < 64 * 16; i += 256) {
        int row = i >> 4, k = i & 15;
        EA[row * 32 + 16 + k] = 0;
    }

    short8 wf[4];
    float ebv[4];
    #pragma unroll
    for (int nt = 0; nt < 4; ++nt) {
        wf[nt]  = *(const short8*)&ew1T[(size_t)(ncol + nt * 16) * 32 + quad * 8];
        ebv[nt] = eb1[ncol + nt * 16];
    }
    __syncthreads();

    const int e_start = rsL[0], e_end = rsL[32];

    floatx4 c2[2][4];
    #pragma unroll
    for (int mt = 0; mt < 2; ++mt)
        #pragma unroll
        for (int nt = 0; nt < 4; ++nt)
            c2[mt][nt] = {0.f, 0.f, 0.f, 0.f};

    for (int w0 = e_start; w0 < e_end; w0 += 64) {
        for (int i = tid; i < 64 * 16; i += 256) {
            int row = i >> 4, k = i & 15;
            int e = w0 + row;
            float v = (e < e_end) ? ea_csr[(size_t)e * ED + k] : 0.f;
            EA[row * 32 + k] = f2bf(v);
        }
        for (int i = tid; i < 32 * 64; i += 256) {
            int nd = i >> 6, el = i & 63;
            int e = w0 + el;
            S[nd * 68 + el] = (e >= rsL[nd] && e < rsL[nd + 1]) ? (short)0x3F80 : (short)0;
        }
        __syncthreads();

        floatx4 c1[4][4];
        #pragma unroll
        for (int nt = 0; nt < 4; ++nt)
            #pragma unroll
            for (int mt = 0; mt < 4; ++mt) {
                c1[mt][nt][0] = ebv[nt]; c1[mt][nt][1] = ebv[nt];
                c1[mt][nt][2] = ebv[nt]; c1[mt][nt][3] = ebv[nt];
            }
        short8 a[4];
        #pragma unroll
        for (int mt = 0; mt < 4; ++mt)
            a[mt] = *(const short8*)&EA[(mt * 16 + lm) * 32 + quad * 8];
        #pragma unroll
        for (int mt = 0; mt < 4; ++mt)
            #pragma unroll
            for (int nt = 0; nt < 4; ++nt)
                c1[mt][nt] = __builtin_amdgcn_mfma_f32_16x16x32_bf16(a[mt], wf[nt], c1[mt][nt], 0, 0, 0);
        #pragma unroll
        for (int mt = 0; mt < 4; ++mt)
            #pragma unroll
            for (int nt = 0; nt < 4; ++nt) {
                sv4 o = {f2bf(fmaxf(c1[mt][nt][0], 0.f)), f2bf(fmaxf(c1[mt][nt][1], 0.f)),
                         f2bf(fmaxf(c1[mt][nt][2], 0.f)), f2bf(fmaxf(c1[mt][nt][3], 0.f))};
                *(sv4*)&RT[(ncol + nt * 16) * 68 + mt * 16 + quad * 4] = o;
            }
        __syncthreads();

        #pragma unroll
        for (int ks = 0; ks < 2; ++ks) {
            short8 a2[2], b2[4];
            #pragma unroll
            for (int mt = 0; mt < 2; ++mt)
                a2[mt] = *(const short8*)&S[(mt * 16 + lm) * 68 + ks * 32 + quad * 8];
            #pragma unroll
            for (int nt = 0; nt < 4; ++nt)
                b2[nt] = *(const short8*)&RT[(ncol + nt * 16) * 68 + ks * 32 + quad * 8];
            #pragma unroll
            for (int mt = 0; mt < 2; ++mt)
                #pragma unroll
                for (int nt = 0; nt < 4; ++nt)
                    c2[mt][nt] = __builtin_amdgcn_mfma_f32_16x16x32_bf16(a2[mt], b2[nt], c2[mt][nt], 0, 0, 0);
        }
        __syncthreads();
    }

    #pragma unroll
    for (int mt = 0; mt < 2; ++mt)
        #pragma unroll
        for (int r = 0; r < 4; ++r) {
            int row = mt * 16 + quad * 4 + r;
            if (row < nvalid) {
                #pragma unroll
                for (int nt = 0; nt < 4; ++nt)
                    haggB[(size_t)(n0 + row) * H + ncol + nt * 16] = f2bf(c2[mt][nt][r]);
            }
        }
}

// ---------------------------------------------------------------------------
// Neighbor gather: agg_bf[n] = bf16( sum_{e: dst=n} h_in_bf[src_e] )
// ---------------------------------------------------------------------------
__global__ __launch_bounds__(256) void gather_kernel(
    const short* __restrict__ h_in_bf,
    const int* __restrict__ rs, const int* __restrict__ csr_src,
    short* __restrict__ agg_bf)
{
    const int lane = threadIdx.x & 63;
    const int wave = threadIdx.x >> 6;
    const int n = blockIdx.x * 4 + wave;
    if (n >= N) return;
    const int s = rs[n], e = rs[n + 1];
    float4 acc = {0.f, 0.f, 0.f, 0.f};
    int j = s;
    for (; j + 4 <= e; j += 4) {
        const int s0 = csr_src[j],     s1 = csr_src[j + 1];
        const int s2 = csr_src[j + 2], s3 = csr_src[j + 3];
        sv4 v0 = *(const sv4*)&h_in_bf[(size_t)s0 * H + 4 * lane];
        sv4 v1 = *(const sv4*)&h_in_bf[(size_t)s1 * H + 4 * lane];
        sv4 v2 = *(const sv4*)&h_in_bf[(size_t)s2 * H + 4 * lane];
        sv4 v3 = *(const sv4*)&h_in_bf[(size_t)s3 * H + 4 * lane];
        acc.x += (bf2f(v0.x) + bf2f(v1.x)) + (bf2f(v2.x) + bf2f(v3.x));
        acc.y += (bf2f(v0.y) + bf2f(v1.y)) + (bf2f(v2.y) + bf2f(v3.y));
        acc.z += (bf2f(v0.z) + bf2f(v1.z)) + (bf2f(v2.z) + bf2f(v3.z));
        acc.w += (bf2f(v0.w) + bf2f(v1.w)) + (bf2f(v2.w) + bf2f(v3.w));
    }
    for (; j < e; ++j) {
        const int s0 = csr_src[j];
        sv4 v0 = *(const sv4*)&h_in_bf[(size_t)s0 * H + 4 * lane];
        acc.x += bf2f(v0.x); acc.y += bf2f(v0.y);
        acc.z += bf2f(v0.z); acc.w += bf2f(v0.w);
    }
    sv4 o = {f2bf(acc.x), f2bf(acc.y), f2bf(acc.z), f2bf(acc.w)};
    *(sv4*)&agg_bf[(size_t)n * H + 4 * lane] = o;
}

// ---------------------------------------------------------------------------
// Weight prep. Algebraic fusion: u = relu( agg@(Wx.W1) + hagg@(We'.W1)
//                                         + deg*(be2.W1) + b1 )
// ---------------------------------------------------------------------------
__global__ __launch_bounds__(256) void we_fuse_kernel(
    const float* __restrict__ ee_w2, const float* __restrict__ msge_w,
    float* __restrict__ WEf32)
{
    __shared__ float wrow[H];
    const int tid = threadIdx.x;
    const int l = blockIdx.x / H;
    const int t = blockIdx.x % H;
    wrow[tid] = ee_w2[t * H + tid];
    __syncthreads();
    const float* mw = msge_w + (size_t)l * H * H;
    float acc = 0.f;
    for (int k = 0; k < H; ++k)
        acc += wrow[k] * mw[k * H + tid];
    WEf32[((size_t)l * H + t) * H + tid] = acc;
}

__global__ __launch_bounds__(256) void fuse1_kernel(
    const float* __restrict__ msgx_w, const float* __restrict__ upd_w1,
    short* __restrict__ fusedT)
{
    __shared__ float wrow[H];
    const int tid = threadIdx.x;
    const int l = blockIdx.x / H;
    const int t = blockIdx.x % H;
    wrow[tid] = msgx_w[((size_t)l * H + t) * H + tid];
    __syncthreads();
    const float* w1 = upd_w1 + (size_t)l * H * H;
    float acc = 0.f;
    for (int j = 0; j < H; ++j)
        acc += wrow[j] * w1[j * H + tid];
    fusedT[((size_t)(l * H + tid)) * 512 + t] = f2bf(acc);
}

__global__ __launch_bounds__(256) void fuse2_kernel(
    const float* __restrict__ WEf32, const float* __restrict__ upd_w1,
    short* __restrict__ fusedT)
{
    __shared__ float wrow[H];
    const int tid = threadIdx.x;
    const int l = blockIdx.x / H;
    const int t = blockIdx.x % H;
    wrow[tid] = WEf32[((size_t)l * H + t) * H + tid];
    __syncthreads();
    const float* w1 = upd_w1 + (size_t)l * H * H;
    float acc = 0.f;
    for (int j = 0; j < H; ++j)
        acc += wrow[j] * w1[j * H + tid];
    fusedT[((size_t)(l * H + tid)) * 512 + 256 + t] = f2bf(acc);
}

__global__ __launch_bounds__(256) void fuse_b_kernel(
    const float* __restrict__ ee_b2, const float* __restrict__ msge_w,
    float* __restrict__ be2)
{
    __shared__ float brow[H];
    const int tid = threadIdx.x;
    const int l = blockIdx.x;
    brow[tid] = ee_b2[tid];
    __syncthreads();
    const float* mw = msge_w + (size_t)l * H * H;
    float acc = 0.f;
    for (int k = 0; k < H; ++k)
        acc += brow[k] * mw[k * H + tid];
    be2[l * H + tid] = acc;
}

__global__ __launch_bounds__(256) void fuse_bias_kernel(
    const float* __restrict__ be2, const float* __restrict__ upd_w1,
    float* __restrict__ be2w1)
{
    __shared__ float brow[H];
    const int tid = threadIdx.x;
    const int l = blockIdx.x;
    brow[tid] = be2[l * H + tid];
    __syncthreads();
    const float* w1 = upd_w1 + (size_t)l * H * H;
    float acc = 0.f;
    for (int j = 0; j < H; ++j)
        acc += brow[j] * w1[j * H + tid];
    be2w1[l * H + tid] = acc;
}

__global__ __launch_bounds__(256) void conv_bt_kernel(
    const float* __restrict__ w, short* __restrict__ bt)
{
    int mat = blockIdx.x >> 8, k = blockIdx.x & 255, n = threadIdx.x;
    bt[((size_t)mat * H + n) * H + k] = f2bf(w[((size_t)mat * H + k) * H + n]);
}

__global__ __launch_bounds__(256) void geow_bt_kernel(
    const float* __restrict__ w, short* __restrict__ bt)
{
    for (int i = threadIdx.x; i < 32 * 128; i += 256) {
        int n = i >> 7, k = i & 127;
        bt[i] = f2bf(w[k * 32 + n]);
    }
}

__global__ __launch_bounds__(256) void ninw1_bt_kernel(
    const float* __restrict__ w, short* __restrict__ bt)
{
    int i = blockIdx.x * 256 + threadIdx.x;
    int n = i >> 6, k = i & 63;
    bt[i] = f2bf(w[k * H + n]);
}

// ew1T[col][k] = bf16(ew1[k][col]) for k<16, 0 for k in 16..31 (K-pad)
__global__ __launch_bounds__(256) void ew1t_kernel(
    const float* __restrict__ ew1, short* __restrict__ ew1T)
{
    int t = threadIdx.x;
    #pragma unroll
    for (int k = 0; k < ED; ++k)
        ew1T[t * 32 + k] = f2bf(ew1[k * H + t]);
    #pragma unroll
    for (int k = ED; k < 32; ++k)
        ew1T[t * 32 + k] = 0;
}

// ---------------------------------------------------------------------------
// Node input encoder (MFMA). M=64 nodes/block. Writes h_bf (bf16 only).
// ---------------------------------------------------------------------------
__global__ __launch_bounds__(256) void node_in_mfma_kernel(
    const float* __restrict__ x,
    const short* __restrict__ geo_wbt, const float* __restrict__ geo_b,
    const short* __restrict__ w1bt, const float* __restrict__ b1,
    const short* __restrict__ w2bt, const float* __restrict__ b2,
    short* __restrict__ h_bf)
{
    constexpr int KP = H + 8;
    constexpr int KX = 128 + 8;
    constexpr int KI = 64 + 8;
    __shared__ short A[64 * KP];
    __shared__ short XIN[64 * KI];
    const int tid = threadIdx.x;
    const int lane = tid & 63, wave = tid >> 6;
    const int quad = lane >> 4, lm = lane & 15;
    const int n0 = blockIdx.x * 64;
    const int nvalid = min(64, N - n0);
    const int ncol = wave * 64 + lm;

    for (int i = tid; i < 64 * 128; i += 256) {
        int row = i >> 7, k = i & 127;
        float v = (row < nvalid) ? x[(size_t)(n0 + row) * XD + k] : 0.f;
        A[row * KX + k] = f2bf(v);
    }
    for (int i = tid; i < 64 * 32; i += 256) {
        int row = i >> 5, k = i & 31;
        float v = (row < nvalid) ? x[(size_t)(n0 + row) * XD + 128 + k] : 0.f;
        XIN[row * KI + 32 + k] = f2bf(v);
    }
    __syncthreads();

    // geo GEMM
    {
        floatx4 c[2];
        float b0 = geo_b[lm], b1v = geo_b[16 + lm];
        c[0] = {b0, b0, b0, b0};
        c[1] = {b1v, b1v, b1v, b1v};
        #pragma unroll
        for (int ks = 0; ks < 4; ++ks) {
            short8 a  = *(const short8*)&A[(wave * 16 + lm) * KX + ks * 32 + quad * 8];
            short8 w0 = *(const short8*)&geo_wbt[(size_t)lm * 128 + ks * 32 + quad * 8];
            short8 w1 = *(const short8*)&geo_wbt[(size_t)(16 + lm) * 128 + ks * 32 + quad * 8];
            c[0] = __builtin_amdgcn_mfma_f32_16x16x32_bf16(a, w0, c[0], 0, 0, 0);
            c[1] = __builtin_amdgcn_mfma_f32_16x16x32_bf16(a, w1, c[1], 0, 0, 0);
        }
        #pragma unroll
        for (int nt = 0; nt < 2; ++nt)
            #pragma unroll
            for (int r = 0; r < 4; ++r) {
                int row = wave * 16 + quad * 4 + r;
                XIN[row * KI + nt * 16 + lm] = f2bf(fmaxf(c[nt][r], 0.f));
            }
    }
    __syncthreads();

    // GEMM1: K=64 -> hid (relu) into A
    floatx4 c1[4][4];
    #pragma unroll
    for (int nt = 0; nt < 4; ++nt) {
        float bb = b1[ncol + nt * 16];
        #pragma unroll
        for (int mt = 0; mt < 4; ++mt) {
            c1[mt][nt][0] = bb; c1[mt][nt][1] = bb;
            c1[mt][nt][2] = bb; c1[mt][nt][3] = bb;
        }
    }
    #pragma unroll
    for (int ks = 0; ks < 2; ++ks) {
        short8 a[4], b[4];
        #pragma unroll
        for (int mt = 0; mt < 4; ++mt)
            a[mt] = *(const short8*)&XIN[(mt * 16 + lm) * KI + ks * 32 + quad * 8];
        #pragma unroll
        for (int nt = 0; nt < 4; ++nt)
            b[nt] = *(const short8*)&w1bt[(size_t)(ncol + nt * 16) * 64 + ks * 32 + quad * 8];
        #pragma unroll
        for (int mt = 0; mt < 4; ++mt)
            #pragma unroll
            for (int nt = 0; nt < 4; ++nt)
                c1[mt][nt] = __builtin_amdgcn_mfma_f32_16x16x32_bf16(a[mt], b[nt], c1[mt][nt], 0, 0, 0);
    }
    __syncthreads();
    #pragma unroll
    for (int mt = 0; mt < 4; ++mt)
        #pragma unroll
        for (int nt = 0; nt < 4; ++nt) {
            int col = ncol + nt * 16;
            #pragma unroll
            for (int r = 0; r < 4; ++r) {
                int row = mt * 16 + quad * 4 + r;
                A[row * KP + col] = f2bf(fmaxf(c1[mt][nt][r], 0.f));
            }
        }
    __syncthreads();

    // GEMM2: K=256 -> h_bf
    floatx4 c2[4][4];
    #pragma unroll
    for (int nt = 0; nt < 4; ++nt) {
        float bb = b2[ncol + nt * 16];
        #pragma unroll
        for (int mt = 0; mt < 4; ++mt) {
            c2[mt][nt][0] = bb; c2[mt][nt][1] = bb;
            c2[mt][nt][2] = bb; c2[mt][nt][3] = bb;
        }
    }
    #pragma unroll
    for (int ks = 0; ks < 8; ++ks) {
        short8 a[4], b[4];
        #pragma unroll
        for (int mt = 0; mt < 4; ++mt)
            a[mt] = *(const short8*)&A[(mt * 16 + lm) * KP + ks * 32 + quad * 8];
        #pragma unroll
        for (int nt = 0; nt < 4; ++nt)
            b[nt] = *(const short8*)&w2bt[(size_t)(ncol + nt * 16) * H + ks * 32 + quad * 8];
        #pragma unroll
        for (int mt = 0; mt < 4; ++mt)
            #pragma unroll
            for (int nt = 0; nt < 4; ++nt)
                c2[mt][nt] = __builtin_amdgcn_mfma_f32_16x16x32_bf16(a[mt], b[nt], c2[mt][nt], 0, 0, 0);
    }
    #pragma unroll
    for (int mt = 0; mt < 4; ++mt)
        #pragma unroll
        for (int r = 0; r < 4; ++r) {
            int row = mt * 16 + quad * 4 + r;
            if (row < nvalid) {
                #pragma unroll
                for (int nt = 0; nt < 4; ++nt)
                    h_bf[(size_t)(n0 + row) * H + ncol + nt * 16] = f2bf(c2[mt][nt][r]);
            }
        }
}

// ---------------------------------------------------------------------------
// Fused layer kernel, M=16 nodes/block, 3 GEMM passes. Grid 3125 blocks,
// LDS ~18 KB, <=64 VGPR (launch_bounds 256,8) -> up to 8 blocks/CU.
// NOTE: agg_bf aliases the output ping-pong buffer: each block reads only its
// own 16 rows (stage 1) and overwrites exactly those rows at the end.
// ---------------------------------------------------------------------------
__global__ __launch_bounds__(256, 8) void layer_kernel(
    const short* __restrict__ h_in_bf, short* __restrict__ h_out_bf,
    float* __restrict__ h_out_f32,
    const short* __restrict__ agg_bf,
    const int* __restrict__ rs,
    const short* __restrict__ haggB,
    const short* __restrict__ fusedT, const float* __restrict__ be2w1,
    const float* __restrict__ b1,
    const short* __restrict__ u2bt, const float* __restrict__ b2,
    const float* __restrict__ lng, const float* __restrict__ lnb)
{
    constexpr int KP = H + 8;
    constexpr int M  = 16;
    constexpr int MT = M / 16;     // 1
    __shared__ short A[M * KP];
    __shared__ short A2[M * KP];
    __shared__ int rsL[M + 1];
    __shared__ float psum[M][4], psq[M][4];
    __shared__ float muS[M], rsS[M];
    const int tid  = threadIdx.x;
    const int lane = tid & 63, wave = tid >> 6;
    const int quad = lane >> 4, lm = lane & 15;
    const int n0 = blockIdx.x * M;
    const int nvalid = min(M, N - n0);
    const int ncol = wave * 64 + lm;

    if (tid < M + 1) rsL[tid] = rs[min(n0 + tid, N)];
    // --- stage 1: stream BOTH input tiles (agg -> A, hagg -> A2) ---
    for (int i = tid; i < M * 64; i += 256) {
        int row = i >> 6, q = i & 63;
        sv4 v = {0, 0, 0, 0};
        sv4 w = {0, 0, 0, 0};
        if (row < nvalid) {
            v = *(const sv4*)&agg_bf[(size_t)(n0 + row) * H + 4 * q];
            w = *(const sv4*)&haggB[(size_t)(n0 + row) * H + 4 * q];
        }
        *(sv4*)&A[row * KP + 4 * q]  = v;
        *(sv4*)&A2[row * KP + 4 * q] = w;
    }
    __syncthreads();            // barrier 1

    // --- stage 2: fused K=512 GEMM -> u_pre; acc init deg*be2w1 + b1 ---
    floatx4 c1[MT][4];
    #pragma unroll
    for (int nt = 0; nt < 4; ++nt) {
        float bw = be2w1[ncol + nt * 16];
        float bb = b1[ncol + nt * 16];
        #pragma unroll
        for (int mt = 0; mt < MT; ++mt) {
            #pragma unroll
            for (int r = 0; r < 4; ++r) {
                int row = mt * 16 + quad * 4 + r;
                float deg = (float)(rsL[row + 1] - rsL[row]);
                c1[mt][nt][r] = deg * bw + bb;
            }
        }
    }
    // pass A: agg vs F1 (fusedT cols 0..255), double-buffered weight frags
    {
        short8 bcur[4], bnxt[4];
        #pragma unroll
        for (int nt = 0; nt < 4; ++nt)
            bcur[nt] = *(const short8*)&fusedT[(size_t)(ncol + nt * 16) * 512 + quad * 8];
        #pragma unroll
        for (int ks = 0; ks < 8; ++ks) {
            if (ks < 7) {
                #pragma unroll
                for (int nt = 0; nt < 4; ++nt)
                    bnxt[nt] = *(const short8*)&fusedT[(size_t)(ncol + nt * 16) * 512 + (ks + 1) * 32 + quad * 8];
            }
            short8 a[MT];
            #pragma unroll
            for (int mt = 0; mt < MT; ++mt)
                a[mt] = *(const short8*)&A[(mt * 16 + lm) * KP + ks * 32 + quad * 8];
            #pragma unroll
            for (int mt = 0; mt < MT; ++mt)
                #pragma unroll
                for (int nt = 0; nt < 4; ++nt)
                    c1[mt][nt] = __builtin_amdgcn_mfma_f32_16x16x32_bf16(a[mt], bcur[nt], c1[mt][nt], 0, 0, 0);
            #pragma unroll
            for (int nt = 0; nt < 4; ++nt) bcur[nt] = bnxt[nt];
        }
    }
    // pass B: hagg vs F2 (fusedT cols 256..511)
    {
        short8 bcur[4], bnxt[4];
        #pragma unroll
        for (int nt = 0; nt < 4; ++nt)
            bcur[nt] = *(const short8*)&fusedT[(size_t)(ncol + nt * 16) * 512 + 256 + quad * 8];
        #pragma unroll
        for (int ks = 0; ks < 8; ++ks) {
            if (ks < 7) {
                #pragma unroll
                for (int nt = 0; nt < 4; ++nt)
                    bnxt[nt] = *(const short8*)&fusedT[(size_t)(ncol + nt * 16) * 512 + 256 + (ks + 1) * 32 + quad * 8];
            }
            short8 a[MT];
            #pragma unroll
            for (int mt = 0; mt < MT; ++mt)
                a[mt] = *(const short8*)&A2[(mt * 16 + lm) * KP + ks * 32 + quad * 8];
            #pragma unroll
            for (int mt = 0; mt < MT; ++mt)
                #pragma unroll
                for (int nt = 0; nt < 4; ++nt)
                    c1[mt][nt] = __builtin_amdgcn_mfma_f32_16x16x32_bf16(a[mt], bcur[nt], c1[mt][nt], 0, 0, 0);
            #pragma unroll
            for (int nt = 0; nt < 4; ++nt) bcur[nt] = bnxt[nt];
        }
    }
    __syncthreads();            // barrier 2 (all reads of A/A2 done)
    // write relu(u_pre) -> A
    #pragma unroll
    for (int mt = 0; mt < MT; ++mt)
        #pragma unroll
        for (int nt = 0; nt < 4; ++nt) {
            int col = ncol + nt * 16;
            #pragma unroll
            for (int r = 0; r < 4; ++r) {
                int row = mt * 16 + quad * 4 + r;
                A[row * KP + col] = f2bf(fmaxf(c1[mt][nt][r], 0.f));
            }
        }
    __syncthreads();            // barrier 3

    // --- stage 3: GEMM K=256 @W2 + b2 + residual; LN; store ---
    floatx4 c3[MT][4];
    #pragma unroll
    for (int nt = 0; nt < 4; ++nt) {
        float bb = b2[ncol + nt * 16];
        #pragma unroll
        for (int mt = 0; mt < MT; ++mt) {
            c3[mt][nt][0] = bb; c3[mt][nt][1] = bb;
            c3[mt][nt][2] = bb; c3[mt][nt][3] = bb;
        }
    }
    {
        short8 bcur[4], bnxt[4];
        #pragma unroll
        for (int nt = 0; nt < 4; ++nt)
            bcur[nt] = *(const short8*)&u2bt[(size_t)(ncol + nt * 16) * H + quad * 8];
        #pragma unroll
        for (int ks = 0; ks < 8; ++ks) {
            if (ks < 7) {
                #pragma unroll
                for (int nt = 0; nt < 4; ++nt)
                    bnxt[nt] = *(const short8*)&u2bt[(size_t)(ncol + nt * 16) * H + (ks + 1) * 32 + quad * 8];
            }
            short8 a[MT];
            #pragma unroll
            for (int mt = 0; mt < MT; ++mt)
                a[mt] = *(const short8*)&A[(mt * 16 + lm) * KP + ks * 32 + quad * 8];
            #pragma unroll
            for (int mt = 0; mt < MT; ++mt)
                #pragma unroll
                for (int nt = 0; nt < 4; ++nt)
                    c3[mt][nt] = __builtin_amdgcn_mfma_f32_16x16x32_bf16(a[mt], bcur[nt], c3[mt][nt], 0, 0, 0);
            #pragma unroll
            for (int nt = 0; nt < 4; ++nt) bcur[nt] = bnxt[nt];
        }
    }
    #pragma unroll
    for (int mt = 0; mt < MT; ++mt)
        #pragma unroll
        for (int r = 0; r < 4; ++r) {
            int row = mt * 16 + quad * 4 + r;
            if (row < nvalid) {
                #pragma unroll
                for (int nt = 0; nt < 4; ++nt)
                    c3[mt][nt][r] += bf2f(h_in_bf[(size_t)(n0 + row) * H + ncol + nt * 16]);
            }
        }

    // LN partials
    #pragma unroll
    for (int mt = 0; mt < MT; ++mt)
        #pragma unroll
        for (int r = 0; r < 4; ++r) {
            float s = 0.f, q = 0.f;
            #pragma unroll
            for (int nt = 0; nt < 4; ++nt) {
                float v = c3[mt][nt][r];
                s += v; q += v * v;
            }
            #pragma unroll
            for (int m = 1; m < 16; m <<= 1) {
                s += __shfl_xor(s, m, 64);
                q += __shfl_xor(q, m, 64);
            }
            if (lm == 0) {
                int row = mt * 16 + quad * 4 + r;
                psum[row][wave] = s;
                psq[row][wave]  = q;
            }
        }
    __syncthreads();            // barrier 4
    if (tid < M) {
        float s = psum[tid][0] + psum[tid][1] + psum[tid][2] + psum[tid][3];
        float q = psq[tid][0] + psq[tid][1] + psq[tid][2] + psq[tid][3];
        float mu = s * (1.f / H);
        float var = q * (1.f / H) - mu * mu;
        muS[tid] = mu;
        rsS[tid] = rsqrtf(fmaxf(var, 0.f) + 1e-5f);
    }
    __syncthreads();            // barrier 5

    float g[4], bb4[4];
    #pragma unroll
    for (int nt = 0; nt < 4; ++nt) {
        g[nt]   = lng[ncol + nt * 16];
        bb4[nt] = lnb[ncol + nt * 16];
    }
    const bool wbf = (h_out_bf != nullptr);
    const bool wf  = (h_out_f32 != nullptr);
    #pragma unroll
    for (int mt = 0; mt < MT; ++mt)
        #pragma unroll
        for (int r = 0; r < 4; ++r) {
            int row = mt * 16 + quad * 4 + r;
            if (row < nvalid) {
                float mu = muS[row], rsv = rsS[row];
                #pragma unroll
                for (int nt = 0; nt < 4; ++nt) {
                    float o = (c3[mt][nt][r] - mu) * rsv * g[nt] + bb4[nt];
                    size_t off = (size_t)(n0 + row) * H + ncol + nt * 16;
                    if (wbf) h_out_bf[off] = f2bf(o);
                    if (wf)  h_out_f32[off] = o;
                }
            }
        }
}

// ---------------------------------------------------------------------------
// Pooling (batch sorted -> LDS accumulate, flush on change)
// ---------------------------------------------------------------------------
__global__ __launch_bounds__(256) void pool_kernel(
    const float* __restrict__ h, const int* __restrict__ batch,
    const int* __restrict__ ntype,
    float* __restrict__ zsum, float* __restrict__ zcnt)
{
    constexpr int CHUNK = 256;
    __shared__ float acc[3][H];
    __shared__ float cnt[3];
    const int tid = threadIdx.x;
    const int n0 = blockIdx.x * CHUNK;
    const int nend = min(n0 + CHUNK, N);

    for (int q = 0; q < 3; ++q) acc[q][tid] = 0.f;
    if (tid == 0) { cnt[0] = 0.f; cnt[1] = 0.f; cnt[2] = 0.f; }
    __syncthreads();

    int cur = batch[n0];
    for (int n = n0; n < nend; ++n) {
        int b = batch[n];
        int t = ntype[n];
        if (b != cur) {
            for (int q = 0; q < 3; ++q) {
                atomicAdd(&zsum[cur * (3 * H) + q * H + tid], acc[q][tid]);
                acc[q][tid] = 0.f;
            }
            if (tid == 0)
                for (int q = 0; q < 3; ++q) { atomicAdd(&zcnt[cur * 3 + q], cnt[q]); cnt[q] = 0.f; }
            cur = b;
        }
        acc[t][tid] += h[(size_t)n * H + tid];
        if (tid == 0) cnt[t] += 1.f;
    }
    for (int q = 0; q < 3; ++q)
        atomicAdd(&zsum[cur * (3 * H) + q * H + tid], acc[q][tid]);
    if (tid == 0)
        for (int q = 0; q < 3; ++q) atomicAdd(&zcnt[cur * 3 + q], cnt[q]);
}

__global__ __launch_bounds__(256) void finalize_kernel(
    const float* __restrict__ zsum, const float* __restrict__ zcnt,
    float* __restrict__ out)
{
    int idx = blockIdx.x * 256 + threadIdx.x;
    if (idx >= B * 3 * H) return;
    int b = idx / (3 * H);
    int c = idx % (3 * H);
    int t = c / H;
    float cn = zcnt[b * 3 + t];
    out[idx] = zsum[idx] / fmaxf(cn, 1.f);
}

__global__ __launch_bounds__(256) void batch_out_kernel(
    const int* __restrict__ batch, float* __restrict__ out)
{
    int idx = blockIdx.x * 256 + threadIdx.x;
    if (idx < N) out[idx] = (float)batch[idx];
}

// ---------------------------------------------------------------------------
extern "C" void kernel_launch(void* const* d_in, const int* in_sizes, int n_in,
                              void* d_out, int out_size, void* d_ws, size_t ws_size,
                              hipStream_t stream) {
    const float* x         = (const float*)d_in[0];
    const float* edge_attr = (const float*)d_in[1];
    const float* geo_w     = (const float*)d_in[2];
    const float* geo_b     = (const float*)d_in[3];
    const float* nin_w1    = (const float*)d_in[4];
    const float* nin_b1    = (const float*)d_in[5];
    const float* nin_w2    = (const float*)d_in[6];
    const float* nin_b2    = (const float*)d_in[7];
    const float* ee_w1     = (const float*)d_in[8];
    const float* ee_b1     = (const float*)d_in[9];
    const float* ee_w2     = (const float*)d_in[10];
    const float* ee_b2     = (const float*)d_in[11];
    const float* msgx_w    = (const float*)d_in[12];
    const float* msge_w    = (const float*)d_in[13];
    const float* upd_w1    = (const float*)d_in[14];
    const float* upd_b1    = (const float*)d_in[15];
    const float* upd_w2    = (const float*)d_in[16];
    const float* upd_b2    = (const float*)d_in[17];
    const float* ln_g      = (const float*)d_in[18];
    const float* ln_b      = (const float*)d_in[19];
    const int*   edge_index= (const int*)d_in[20];
    const int*   batch     = (const int*)d_in[21];
    const int*   node_type = (const int*)d_in[22];

    float* out = (float*)d_out;
    float* hf  = out + B * 3 * H;                  // final f32 h -> d_out

    // Workspace layout (~104 MB):
    short* h0_bf   = (short*)d_ws;                     // [N,H] bf16  25.6 MB
    short* h1_bf   = h0_bf + (size_t)N * H;            // [N,H] bf16  25.6 MB
    short* haggB   = h1_bf + (size_t)N * H;            // [N,H] bf16  25.6 MB
    short* fusedT  = haggB + (size_t)N * H;            // [L,H,512] bf16 (F1|F2)
    short* u2bt    = fusedT + (size_t)L * H * 512;     // [L,H,H] bf16
    short* geowbt  = u2bt + (size_t)L * H * H;         // [32,128]
    short* w1bt    = geowbt + 32 * 128;                // [H,64]
    short* w2bt    = w1bt + H * 64;                    // [H,H]
    short* ew1T    = w2bt + H * H;                     // [256,32] bf16 K-padded
    float* WEf32   = (float*)(ew1T + 256 * 32);        // [L,H,H] f32 (4 MB)
    float* be2     = WEf32 + (size_t)L * H * H;        // [L,H]
    float* be2w1   = be2 + L * H;                      // [L,H]
    float* zsum    = be2w1 + L * H;                    // [B,3H]
    float* zcnt    = zsum + B * 3 * H;                 // [B,3]
    int*   rowcnt  = (int*)(zcnt + B * 3);             // [N]
    int*   rs      = rowcnt + N;                       // [N+1]
    int*   cursor  = rs + N + 1;                       // [N]
    int*   bsum    = cursor + N;                       // [256]
    int*   csr_src = bsum + 256;                       // [E]
    float* ea_csr  = (float*)(csr_src + E);            // [E,ED] f32 19.2 MB

    const int* src = edge_index;
    const int* dst = edge_index + E;

    const int nscan = (N + 255) / 256;   // 196 blocks <= 256

    // --- CSR build (+ edge-attr reorder) ---
    hipMemsetAsync(rowcnt, 0, (size_t)N * sizeof(int), stream);
    hist_kernel<<<(E + 255) / 256, 256, 0, stream>>>(dst, rowcnt);
    scan_partial_kernel<<<nscan, 256, 0, stream>>>(rowcnt, bsum);
    scan_bsum_kernel<<<1, 256, 0, stream>>>(bsum, nscan, rs + N);
    scan_final_kernel<<<nscan, 256, 0, stream>>>(rowcnt, bsum, rs, cursor);
    fill_kernel<<<(E + 255) / 256, 256, 0, stream>>>(src, dst, edge_attr, cursor, csr_src, ea_csr);

    // --- weight prep (fused weights) ---
    we_fuse_kernel<<<L * H, 256, 0, stream>>>(ee_w2, msge_w, WEf32);
    fuse1_kernel<<<L * H, 256, 0, stream>>>(msgx_w, upd_w1, fusedT);
    fuse2_kernel<<<L * H, 256, 0, stream>>>(WEf32, upd_w1, fusedT);
    fuse_b_kernel<<<L, 256, 0, stream>>>(ee_b2, msge_w, be2);
    fuse_bias_kernel<<<L, 256, 0, stream>>>(be2, upd_w1, be2w1);
    conv_bt_kernel<<<L * 256, 256, 0, stream>>>(upd_w2, u2bt);
    conv_bt_kernel<<<256, 256, 0, stream>>>(nin_w2, w2bt);
    geow_bt_kernel<<<1, 256, 0, stream>>>(geo_w, geowbt);
    ninw1_bt_kernel<<<64, 256, 0, stream>>>(nin_w1, w1bt);
    ew1t_kernel<<<1, 256, 0, stream>>>(ee_w1, ew1T);

    // --- hiddenAgg (layer-independent): MFMA over CSR-contiguous edges ---
    hidden_agg_mfma_kernel<<<(N + 31) / 32, 256, 0, stream>>>(
        ea_csr, ew1T, ee_b1, rs, haggB);

    // --- node encoder -> h0_bf ---
    node_in_mfma_kernel<<<(N + 63) / 64, 256, 0, stream>>>(
        x, geowbt, geo_b, w1bt, nin_b1, w2bt, nin_b2, h0_bf);

    // --- layers: bf16 ping-pong; gather writes into the out buffer (safe:
    // each layer block reads only its own rows, then overwrites them) ---
    const int lgrid = (N + 15) / 16;
    for (int l = 0; l < L; ++l) {
        const short* hin  = (l & 1) ? h1_bf : h0_bf;
        short* aggb       = (l & 1) ? h0_bf : h1_bf;   // out ping-pong buffer
        short* hout_bf    = (l == L - 1) ? nullptr : aggb;
        float* hout_f32   = (l == L - 1) ? hf : nullptr;
        gather_kernel<<<(N + 3) / 4, 256, 0, stream>>>(hin, rs, csr_src, aggb);
        layer_kernel<<<lgrid, 256, 0, stream>>>(
            hin, hout_bf, hout_f32, aggb, rs, haggB,
            fusedT + (size_t)l * H * 512, be2w1 + (size_t)l * H,
            upd_b1 + (size_t)l * H,
            u2bt + (size_t)l * H * H, upd_b2 + (size_t)l * H,
            ln_g + (size_t)l * H, ln_b + (size_t)l * H);
    }

    // --- pooling ---
    hipMemsetAsync(zsum, 0, (size_t)(B * 3 * H + B * 3) * sizeof(float), stream);
    pool_kernel<<<(N + 255) / 256, 256, 0, stream>>>(hf, batch, node_type, zsum, zcnt);
    finalize_kernel<<<(B * 3 * H + 255) / 256, 256, 0, stream>>>(zsum, zcnt, out);
    batch_out_kernel<<<(N + 255) / 256, 256, 0, stream>>>(batch, out + B * 3 * H + (size_t)N * H);
}

// Round 12
// 918.337 us; speedup vs baseline: 1.2652x; 1.2652x over previous
//
#include <hip/hip_runtime.h>

// Problem constants (from reference)
constexpr int N  = 50000;
constexpr int E  = 300000;
constexpr int B  = 8;
constexpr int XD = 160;
constexpr int ED = 16;
constexpr int H  = 256;
constexpr int L  = 4;
constexpr int G  = 32;

typedef __attribute__((ext_vector_type(8))) short short8;
typedef __attribute__((ext_vector_type(4))) short sv4;
typedef __attribute__((ext_vector_type(4))) float floatx4;

// f32 -> bf16 round-to-nearest-even
__device__ __forceinline__ short f2bf(float f) {
    union { float f; unsigned u; } v; v.f = f;
    unsigned r = (v.u + 0x7fffu + ((v.u >> 16) & 1u)) >> 16;
    return (short)r;
}
__device__ __forceinline__ float bf2f(short s) {
    union { unsigned u; float f; } v;
    v.u = ((unsigned)(unsigned short)s) << 16;
    return v.f;
}

// ---------------------------------------------------------------------------
// CSR build: histogram, 3-pass multi-block scan, fill (+ edge-attr reorder)
// ---------------------------------------------------------------------------
__global__ __launch_bounds__(256) void hist_kernel(
    const int* __restrict__ dst, int* __restrict__ cnt)
{
    int e = blockIdx.x * 256 + threadIdx.x;
    if (e < E) atomicAdd(&cnt[dst[e]], 1);
}

__global__ __launch_bounds__(256) void scan_partial_kernel(
    const int* __restrict__ cnt, int* __restrict__ bsum)
{
    __shared__ int s[256];
    const int tid = threadIdx.x;
    int i = blockIdx.x * 256 + tid;
    s[tid] = (i < N) ? cnt[i] : 0;
    __syncthreads();
    #pragma unroll
    for (int off = 128; off > 0; off >>= 1) {
        if (tid < off) s[tid] += s[tid + off];
        __syncthreads();
    }
    if (tid == 0) bsum[blockIdx.x] = s[0];
}

__global__ __launch_bounds__(256) void scan_bsum_kernel(
    int* __restrict__ bsum, int nb, int* __restrict__ rsN)
{
    __shared__ int s[256];
    const int tid = threadIdx.x;
    int v = (tid < nb) ? bsum[tid] : 0;
    s[tid] = v;
    __syncthreads();
    #pragma unroll
    for (int off = 1; off < 256; off <<= 1) {
        int x = (tid >= off) ? s[tid - off] : 0;
        __syncthreads();
        s[tid] += x;
        __syncthreads();
    }
    if (tid < nb) bsum[tid] = s[tid] - v;
    if (tid == 255) *rsN = s[255];
}

__global__ __launch_bounds__(256) void scan_final_kernel(
    const int* __restrict__ cnt, const int* __restrict__ bsum,
    int* __restrict__ rs, int* __restrict__ cursor)
{
    __shared__ int s[256];
    const int tid = threadIdx.x;
    int i = blockIdx.x * 256 + tid;
    int v = (i < N) ? cnt[i] : 0;
    s[tid] = v;
    __syncthreads();
    #pragma unroll
    for (int off = 1; off < 256; off <<= 1) {
        int x = (tid >= off) ? s[tid - off] : 0;
        __syncthreads();
        s[tid] += x;
        __syncthreads();
    }
    int excl = s[tid] - v + bsum[blockIdx.x];
    if (i < N) { rs[i] = excl; cursor[i] = excl; }
}

// fill + CSR-reorder of edge attrs: ea_csr[pos] = ea[e].
__global__ __launch_bounds__(256) void fill_kernel(
    const int* __restrict__ src, const int* __restrict__ dst,
    const float* __restrict__ ea,
    int* __restrict__ cursor, int* __restrict__ csr_src,
    float* __restrict__ ea_csr)
{
    int e = blockIdx.x * 256 + threadIdx.x;
    if (e < E) {
        int d = dst[e];
        int pos = atomicAdd(&cursor[d], 1);
        csr_src[pos] = src[e];
        const float4* a = (const float4*)(ea + (size_t)e * ED);
        float4* o = (float4*)(ea_csr + (size_t)pos * ED);
        o[0] = a[0]; o[1] = a[1]; o[2] = a[2]; o[3] = a[3];
    }
}

// ---------------------------------------------------------------------------
// hiddenAgg via MFMA: per block, 32 nodes; loop 64-edge windows of the
// CSR-contiguous edge range.
//   GEMM1: R = relu(EA @ W + b)           (edges x 256, K=32 zero-padded)
//   GEMM2: hagg += S @ R                   (nodes x 256, K=64)
// ---------------------------------------------------------------------------
__global__ __launch_bounds__(256, 3) void hidden_agg_mfma_kernel(
    const float* __restrict__ ea_csr,
    const short* __restrict__ ew1T, const float* __restrict__ eb1,
    const int* __restrict__ rs,
    short* __restrict__ haggB)
{
    __shared__ short EA[64 * 32];      // [edge][k] bf16, k 16..31 zero
    __shared__ short RT[256 * 68];     // [col][edge] bf16
    __shared__ short S [32 * 68];      // [node][edge] bf16 0/1
    __shared__ int rsL[33];
    const int tid  = threadIdx.x;
    const int lane = tid & 63, wave = tid >> 6;
    const int quad = lane >> 4, lm = lane & 15;
    const int n0 = blockIdx.x * 32;
    const int nvalid = min(32, N - n0);
    const int ncol = wave * 64 + lm;

    if (tid < 33) rsL[tid] = rs[min(n0 + tid, N)];
    for (int i = tid; i < 64 * 16; i += 256) {
        int row = i >> 4, k = i & 15;
        EA[row * 32 + 16 + k] = 0;
    }

    short8 wf[4];
    float ebv[4];
    #pragma unroll
    for (int nt = 0; nt < 4; ++nt) {
        wf[nt]  = *(const short8*)&ew1T[(size_t)(ncol + nt * 16) * 32 + quad * 8];
        ebv[nt] = eb1[ncol + nt * 16];
    }
    __syncthreads();

    const int e_start = rsL[0], e_end = rsL[32];

    floatx4 c2[2][4];
    #pragma unroll
    for (int mt = 0; mt < 2; ++mt)
        #pragma unroll
        for (int nt = 0; nt < 4; ++nt)
            c2[mt][nt] = {0.f, 0.f, 0.f, 0.f};

    for (int w0 = e_start; w0 < e_end; w0 += 64) {
        for (int i = tid; i < 64 * 16; i += 256) {
            int row = i >> 4, k = i & 15;
            int e = w0 + row;
            float v = (e < e_end) ? ea_csr[(size_t)e * ED + k] : 0.f;
            EA[row * 32 + k] = f2bf(v);
        }
        for (int i = tid; i < 32 * 64; i += 256) {
            int nd = i >> 6, el = i & 63;
            int e = w0 + el;
            S[nd * 68 + el] = (e >= rsL[nd] && e < rsL[nd + 1]) ? (short)0x3F80 : (short)0;
        }
        __syncthreads();

        floatx4 c1[4][4];
        #pragma unroll
        for (int nt = 0; nt < 4; ++nt)
            #pragma unroll
            for (int mt = 0; mt < 4; ++mt) {
                c1[mt][nt][0] = ebv[nt]; c1[mt][nt][1] = ebv[nt];
                c1[mt][nt][2] = ebv[nt]; c1[mt][nt][3] = ebv[nt];
            }
        short8 a[4];
        #pragma unroll
        for (int mt = 0; mt < 4; ++mt)
            a[mt] = *(const short8*)&EA[(mt * 16 + lm) * 32 + quad * 8];
        #pragma unroll
        for (int mt = 0; mt < 4; ++mt)
            #pragma unroll
            for (int nt = 0; nt < 4; ++nt)
                c1[mt][nt] = __builtin_amdgcn_mfma_f32_16x16x32_bf16(a[mt], wf[nt], c1[mt][nt], 0, 0, 0);
        #pragma unroll
        for (int mt = 0; mt < 4; ++mt)
            #pragma unroll
            for (int nt = 0; nt < 4; ++nt) {
                sv4 o = {f2bf(fmaxf(c1[mt][nt][0], 0.f)), f2bf(fmaxf(c1[mt][nt][1], 0.f)),
                         f2bf(fmaxf(c1[mt][nt][2], 0.f)), f2bf(fmaxf(c1[mt][nt][3], 0.f))};
                *(sv4*)&RT[(ncol + nt * 16) * 68 + mt * 16 + quad * 4] = o;
            }
        __syncthreads();

        #pragma unroll
        for (int ks = 0; ks < 2; ++ks) {
            short8 a2[2], b2[4];
            #pragma unroll
            for (int mt = 0; mt < 2; ++mt)
                a2[mt] = *(const short8*)&S[(mt * 16 + lm) * 68 + ks * 32 + quad * 8];
            #pragma unroll
            for (int nt = 0; nt < 4; ++nt)
                b2[nt] = *(const short8*)&RT[(ncol + nt * 16) * 68 + ks * 32 + quad * 8];
            #pragma unroll
            for (int mt = 0; mt < 2; ++mt)
                #pragma unroll
                for (int nt = 0; nt < 4; ++nt)
                    c2[mt][nt] = __builtin_amdgcn_mfma_f32_16x16x32_bf16(a2[mt], b2[nt], c2[mt][nt], 0, 0, 0);
        }
        __syncthreads();
    }

    #pragma unroll
    for (int mt = 0; mt < 2; ++mt)
        #pragma unroll
        for (int r = 0; r < 4; ++r) {
            int row = mt * 16 + quad * 4 + r;
            if (row < nvalid) {
                #pragma unroll
                for (int nt = 0; nt < 4; ++nt)
                    haggB[(size_t)(n0 + row) * H + ncol + nt * 16] = f2bf(c2[mt][nt][r]);
            }
        }
}

// ---------------------------------------------------------------------------
// Neighbor gather: agg_bf[n] = bf16( sum_{e: dst=n} h_in_bf[src_e] )
// ---------------------------------------------------------------------------
__global__ __launch_bounds__(256) void gather_kernel(
    const short* __restrict__ h_in_bf,
    const int* __restrict__ rs, const int* __restrict__ csr_src,
    short* __restrict__ agg_bf)
{
    const int lane = threadIdx.x & 63;
    const int wave = threadIdx.x >> 6;
    const int n = blockIdx.x * 4 + wave;
    if (n >= N) return;
    const int s = rs[n], e = rs[n + 1];
    float4 acc = {0.f, 0.f, 0.f, 0.f};
    int j = s;
    for (; j + 4 <= e; j += 4) {
        const int s0 = csr_src[j],     s1 = csr_src[j + 1];
        const int s2 = csr_src[j + 2], s3 = csr_src[j + 3];
        sv4 v0 = *(const sv4*)&h_in_bf[(size_t)s0 * H + 4 * lane];
        sv4 v1 = *(const sv4*)&h_in_bf[(size_t)s1 * H + 4 * lane];
        sv4 v2 = *(const sv4*)&h_in_bf[(size_t)s2 * H + 4 * lane];
        sv4 v3 = *(const sv4*)&h_in_bf[(size_t)s3 * H + 4 * lane];
        acc.x += (bf2f(v0.x) + bf2f(v1.x)) + (bf2f(v2.x) + bf2f(v3.x));
        acc.y += (bf2f(v0.y) + bf2f(v1.y)) + (bf2f(v2.y) + bf2f(v3.y));
        acc.z += (bf2f(v0.z) + bf2f(v1.z)) + (bf2f(v2.z) + bf2f(v3.z));
        acc.w += (bf2f(v0.w) + bf2f(v1.w)) + (bf2f(v2.w) + bf2f(v3.w));
    }
    for (; j < e; ++j) {
        const int s0 = csr_src[j];
        sv4 v0 = *(const sv4*)&h_in_bf[(size_t)s0 * H + 4 * lane];
        acc.x += bf2f(v0.x); acc.y += bf2f(v0.y);
        acc.z += bf2f(v0.z); acc.w += bf2f(v0.w);
    }
    sv4 o = {f2bf(acc.x), f2bf(acc.y), f2bf(acc.z), f2bf(acc.w)};
    *(sv4*)&agg_bf[(size_t)n * H + 4 * lane] = o;
}

// ---------------------------------------------------------------------------
// Weight prep. Algebraic fusion: u = relu( agg@(Wx.W1) + hagg@(We'.W1)
//                                         + deg*(be2.W1) + b1 )
// ---------------------------------------------------------------------------
__global__ __launch_bounds__(256) void we_fuse_kernel(
    const float* __restrict__ ee_w2, const float* __restrict__ msge_w,
    float* __restrict__ WEf32)
{
    __shared__ float wrow[H];
    const int tid = threadIdx.x;
    const int l = blockIdx.x / H;
    const int t = blockIdx.x % H;
    wrow[tid] = ee_w2[t * H + tid];
    __syncthreads();
    const float* mw = msge_w + (size_t)l * H * H;
    float acc = 0.f;
    for (int k = 0; k < H; ++k)
        acc += wrow[k] * mw[k * H + tid];
    WEf32[((size_t)l * H + t) * H + tid] = acc;
}

__global__ __launch_bounds__(256) void fuse1_kernel(
    const float* __restrict__ msgx_w, const float* __restrict__ upd_w1,
    short* __restrict__ fusedT)
{
    __shared__ float wrow[H];
    const int tid = threadIdx.x;
    const int l = blockIdx.x / H;
    const int t = blockIdx.x % H;
    wrow[tid] = msgx_w[((size_t)l * H + t) * H + tid];
    __syncthreads();
    const float* w1 = upd_w1 + (size_t)l * H * H;
    float acc = 0.f;
    for (int j = 0; j < H; ++j)
        acc += wrow[j] * w1[j * H + tid];
    fusedT[((size_t)(l * H + tid)) * 512 + t] = f2bf(acc);
}

__global__ __launch_bounds__(256) void fuse2_kernel(
    const float* __restrict__ WEf32, const float* __restrict__ upd_w1,
    short* __restrict__ fusedT)
{
    __shared__ float wrow[H];
    const int tid = threadIdx.x;
    const int l = blockIdx.x / H;
    const int t = blockIdx.x % H;
    wrow[tid] = WEf32[((size_t)l * H + t) * H + tid];
    __syncthreads();
    const float* w1 = upd_w1 + (size_t)l * H * H;
    float acc = 0.f;
    for (int j = 0; j < H; ++j)
        acc += wrow[j] * w1[j * H + tid];
    fusedT[((size_t)(l * H + tid)) * 512 + 256 + t] = f2bf(acc);
}

__global__ __launch_bounds__(256) void fuse_b_kernel(
    const float* __restrict__ ee_b2, const float* __restrict__ msge_w,
    float* __restrict__ be2)
{
    __shared__ float brow[H];
    const int tid = threadIdx.x;
    const int l = blockIdx.x;
    brow[tid] = ee_b2[tid];
    __syncthreads();
    const float* mw = msge_w + (size_t)l * H * H;
    float acc = 0.f;
    for (int k = 0; k < H; ++k)
        acc += brow[k] * mw[k * H + tid];
    be2[l * H + tid] = acc;
}

__global__ __launch_bounds__(256) void fuse_bias_kernel(
    const float* __restrict__ be2, const float* __restrict__ upd_w1,
    float* __restrict__ be2w1)
{
    __shared__ float brow[H];
    const int tid = threadIdx.x;
    const int l = blockIdx.x;
    brow[tid] = be2[l * H + tid];
    __syncthreads();
    const float* w1 = upd_w1 + (size_t)l * H * H;
    float acc = 0.f;
    for (int j = 0; j < H; ++j)
        acc += brow[j] * w1[j * H + tid];
    be2w1[l * H + tid] = acc;
}

__global__ __launch_bounds__(256) void conv_bt_kernel(
    const float* __restrict__ w, short* __restrict__ bt)
{
    int mat = blockIdx.x >> 8, k = blockIdx.x & 255, n = threadIdx.x;
    bt[((size_t)mat * H + n) * H + k] = f2bf(w[((size_t)mat * H + k) * H + n]);
}

__global__ __launch_bounds__(256) void geow_bt_kernel(
    const float* __restrict__ w, short* __restrict__ bt)
{
    for (int i = threadIdx.x; i < 32 * 128; i += 256) {
        int n = i >> 7, k = i & 127;
        bt[i] = f2bf(w[k * 32 + n]);
    }
}

__global__ __launch_bounds__(256) void ninw1_bt_kernel(
    const float* __restrict__ w, short* __restrict__ bt)
{
    int i = blockIdx.x * 256 + threadIdx.x;
    int n = i >> 6, k = i & 63;
    bt[i] = f2bf(w[k * H + n]);
}

// ew1T[col][k] = bf16(ew1[k][col]) for k<16, 0 for k in 16..31 (K-pad)
__global__ __launch_bounds__(256) void ew1t_kernel(
    const float* __restrict__ ew1, short* __restrict__ ew1T)
{
    int t = threadIdx.x;
    #pragma unroll
    for (int k = 0; k < ED; ++k)
        ew1T[t * 32 + k] = f2bf(ew1[k * H + t]);
    #pragma unroll
    for (int k = ED; k < 32; ++k)
        ew1T[t * 32 + k] = 0;
}

// ---------------------------------------------------------------------------
// Node input encoder (MFMA). M=64 nodes/block. Writes h_bf (bf16 only).
// ---------------------------------------------------------------------------
__global__ __launch_bounds__(256) void node_in_mfma_kernel(
    const float* __restrict__ x,
    const short* __restrict__ geo_wbt, const float* __restrict__ geo_b,
    const short* __restrict__ w1bt, const float* __restrict__ b1,
    const short* __restrict__ w2bt, const float* __restrict__ b2,
    short* __restrict__ h_bf)
{
    constexpr int KP = H + 8;
    constexpr int KX = 128 + 8;
    constexpr int KI = 64 + 8;
    __shared__ short A[64 * KP];
    __shared__ short XIN[64 * KI];
    const int tid = threadIdx.x;
    const int lane = tid & 63, wave = tid >> 6;
    const int quad = lane >> 4, lm = lane & 15;
    const int n0 = blockIdx.x * 64;
    const int nvalid = min(64, N - n0);
    const int ncol = wave * 64 + lm;

    for (int i = tid; i < 64 * 128; i += 256) {
        int row = i >> 7, k = i & 127;
        float v = (row < nvalid) ? x[(size_t)(n0 + row) * XD + k] : 0.f;
        A[row * KX + k] = f2bf(v);
    }
    for (int i = tid; i < 64 * 32; i += 256) {
        int row = i >> 5, k = i & 31;
        float v = (row < nvalid) ? x[(size_t)(n0 + row) * XD + 128 + k] : 0.f;
        XIN[row * KI + 32 + k] = f2bf(v);
    }
    __syncthreads();

    // geo GEMM
    {
        floatx4 c[2];
        float b0 = geo_b[lm], b1v = geo_b[16 + lm];
        c[0] = {b0, b0, b0, b0};
        c[1] = {b1v, b1v, b1v, b1v};
        #pragma unroll
        for (int ks = 0; ks < 4; ++ks) {
            short8 a  = *(const short8*)&A[(wave * 16 + lm) * KX + ks * 32 + quad * 8];
            short8 w0 = *(const short8*)&geo_wbt[(size_t)lm * 128 + ks * 32 + quad * 8];
            short8 w1 = *(const short8*)&geo_wbt[(size_t)(16 + lm) * 128 + ks * 32 + quad * 8];
            c[0] = __builtin_amdgcn_mfma_f32_16x16x32_bf16(a, w0, c[0], 0, 0, 0);
            c[1] = __builtin_amdgcn_mfma_f32_16x16x32_bf16(a, w1, c[1], 0, 0, 0);
        }
        #pragma unroll
        for (int nt = 0; nt < 2; ++nt)
            #pragma unroll
            for (int r = 0; r < 4; ++r) {
                int row = wave * 16 + quad * 4 + r;
                XIN[row * KI + nt * 16 + lm] = f2bf(fmaxf(c[nt][r], 0.f));
            }
    }
    __syncthreads();

    // GEMM1: K=64 -> hid (relu) into A
    floatx4 c1[4][4];
    #pragma unroll
    for (int nt = 0; nt < 4; ++nt) {
        float bb = b1[ncol + nt * 16];
        #pragma unroll
        for (int mt = 0; mt < 4; ++mt) {
            c1[mt][nt][0] = bb; c1[mt][nt][1] = bb;
            c1[mt][nt][2] = bb; c1[mt][nt][3] = bb;
        }
    }
    #pragma unroll
    for (int ks = 0; ks < 2; ++ks) {
        short8 a[4], b[4];
        #pragma unroll
        for (int mt = 0; mt < 4; ++mt)
            a[mt] = *(const short8*)&XIN[(mt * 16 + lm) * KI + ks * 32 + quad * 8];
        #pragma unroll
        for (int nt = 0; nt < 4; ++nt)
            b[nt] = *(const short8*)&w1bt[(size_t)(ncol + nt * 16) * 64 + ks * 32 + quad * 8];
        #pragma unroll
        for (int mt = 0; mt < 4; ++mt)
            #pragma unroll
            for (int nt = 0; nt < 4; ++nt)
                c1[mt][nt] = __builtin_amdgcn_mfma_f32_16x16x32_bf16(a[mt], b[nt], c1[mt][nt], 0, 0, 0);
    }
    __syncthreads();
    #pragma unroll
    for (int mt = 0; mt < 4; ++mt)
        #pragma unroll
        for (int nt = 0; nt < 4; ++nt) {
            int col = ncol + nt * 16;
            #pragma unroll
            for (int r = 0; r < 4; ++r) {
                int row = mt * 16 + quad * 4 + r;
                A[row * KP + col] = f2bf(fmaxf(c1[mt][nt][r], 0.f));
            }
        }
    __syncthreads();

    // GEMM2: K=256 -> h_bf
    floatx4 c2[4][4];
    #pragma unroll
    for (int nt = 0; nt < 4; ++nt) {
        float bb = b2[ncol + nt * 16];
        #pragma unroll
        for (int mt = 0; mt < 4; ++mt) {
            c2[mt][nt][0] = bb; c2[mt][nt][1] = bb;
            c2[mt][nt][2] = bb; c2[mt][nt][3] = bb;
        }
    }
    #pragma unroll
    for (int ks = 0; ks < 8; ++ks) {
        short8 a[4], b[4];
        #pragma unroll
        for (int mt = 0; mt < 4; ++mt)
            a[mt] = *(const short8*)&A[(mt * 16 + lm) * KP + ks * 32 + quad * 8];
        #pragma unroll
        for (int nt = 0; nt < 4; ++nt)
            b[nt] = *(const short8*)&w2bt[(size_t)(ncol + nt * 16) * H + ks * 32 + quad * 8];
        #pragma unroll
        for (int mt = 0; mt < 4; ++mt)
            #pragma unroll
            for (int nt = 0; nt < 4; ++nt)
                c2[mt][nt] = __builtin_amdgcn_mfma_f32_16x16x32_bf16(a[mt], b[nt], c2[mt][nt], 0, 0, 0);
    }
    #pragma unroll
    for (int mt = 0; mt < 4; ++mt)
        #pragma unroll
        for (int r = 0; r < 4; ++r) {
            int row = mt * 16 + quad * 4 + r;
            if (row < nvalid) {
                #pragma unroll
                for (int nt = 0; nt < 4; ++nt)
                    h_bf[(size_t)(n0 + row) * H + ncol + nt * 16] = f2bf(c2[mt][nt][r]);
            }
        }
}

// ---------------------------------------------------------------------------
// Fused layer kernel, M=32 nodes/block, 3 GEMM passes.
// NOTE: agg_bf aliases the output ping-pong buffer: each block reads only its
// own 32 rows (stage 1) and overwrites exactly those rows at the end.
// ---------------------------------------------------------------------------
__global__ __launch_bounds__(256, 4) void layer_kernel(
    const short* __restrict__ h_in_bf, short* __restrict__ h_out_bf,
    float* __restrict__ h_out_f32,
    const short* __restrict__ agg_bf,
    const int* __restrict__ rs,
    const short* __restrict__ haggB,
    const short* __restrict__ fusedT, const float* __restrict__ be2w1,
    const float* __restrict__ b1,
    const short* __restrict__ u2bt, const float* __restrict__ b2,
    const float* __restrict__ lng, const float* __restrict__ lnb)
{
    constexpr int KP = H + 8;
    constexpr int M  = 32;
    __shared__ short A[M * KP];
    __shared__ short A2[M * KP];
    __shared__ int rsL[M + 1];
    __shared__ float psum[M][4], psq[M][4];
    __shared__ float muS[M], rsS[M];
    const int tid  = threadIdx.x;
    const int lane = tid & 63, wave = tid >> 6;
    const int quad = lane >> 4, lm = lane & 15;
    const int n0 = blockIdx.x * M;
    const int nvalid = min(M, N - n0);
    const int ncol = wave * 64 + lm;

    if (tid < M + 1) rsL[tid] = rs[min(n0 + tid, N)];
    // --- stage 1: stream BOTH input tiles (agg -> A, hagg -> A2) ---
    for (int i = tid; i < M * 64; i += 256) {
        int row = i >> 6, q = i & 63;
        sv4 v = {0, 0, 0, 0};
        sv4 w = {0, 0, 0, 0};
        if (row < nvalid) {
            v = *(const sv4*)&agg_bf[(size_t)(n0 + row) * H + 4 * q];
            w = *(const sv4*)&haggB[(size_t)(n0 + row) * H + 4 * q];
        }
        *(sv4*)&A[row * KP + 4 * q]  = v;
        *(sv4*)&A2[row * KP + 4 * q] = w;
    }
    __syncthreads();            // barrier 1

    // --- stage 2: fused K=512 GEMM -> u_pre; acc init deg*be2w1 + b1 ---
    floatx4 c1[2][4];
    #pragma unroll
    for (int nt = 0; nt < 4; ++nt) {
        float bw = be2w1[ncol + nt * 16];
        float bb = b1[ncol + nt * 16];
        #pragma unroll
        for (int mt = 0; mt < 2; ++mt) {
            #pragma unroll
            for (int r = 0; r < 4; ++r) {
                int row = mt * 16 + quad * 4 + r;
                float deg = (float)(rsL[row + 1] - rsL[row]);
                c1[mt][nt][r] = deg * bw + bb;
            }
        }
    }
    // pass A: agg vs F1 (fusedT cols 0..255), double-buffered weight frags
    {
        short8 bcur[4], bnxt[4];
        #pragma unroll
        for (int nt = 0; nt < 4; ++nt)
            bcur[nt] = *(const short8*)&fusedT[(size_t)(ncol + nt * 16) * 512 + quad * 8];
        #pragma unroll
        for (int ks = 0; ks < 8; ++ks) {
            if (ks < 7) {
                #pragma unroll
                for (int nt = 0; nt < 4; ++nt)
                    bnxt[nt] = *(const short8*)&fusedT[(size_t)(ncol + nt * 16) * 512 + (ks + 1) * 32 + quad * 8];
            }
            short8 a[2];
            #pragma unroll
            for (int mt = 0; mt < 2; ++mt)
                a[mt] = *(const short8*)&A[(mt * 16 + lm) * KP + ks * 32 + quad * 8];
            #pragma unroll
            for (int mt = 0; mt < 2; ++mt)
                #pragma unroll
                for (int nt = 0; nt < 4; ++nt)
                    c1[mt][nt] = __builtin_amdgcn_mfma_f32_16x16x32_bf16(a[mt], bcur[nt], c1[mt][nt], 0, 0, 0);
            #pragma unroll
            for (int nt = 0; nt < 4; ++nt) bcur[nt] = bnxt[nt];
        }
    }
    // pass B: hagg vs F2 (fusedT cols 256..511)
    {
        short8 bcur[4], bnxt[4];
        #pragma unroll
        for (int nt = 0; nt < 4; ++nt)
            bcur[nt] = *(const short8*)&fusedT[(size_t)(ncol + nt * 16) * 512 + 256 + quad * 8];
        #pragma unroll
        for (int ks = 0; ks < 8; ++ks) {
            if (ks < 7) {
                #pragma unroll
                for (int nt = 0; nt < 4; ++nt)
                    bnxt[nt] = *(const short8*)&fusedT[(size_t)(ncol + nt * 16) * 512 + 256 + (ks + 1) * 32 + quad * 8];
            }
            short8 a[2];
            #pragma unroll
            for (int mt = 0; mt < 2; ++mt)
                a[mt] = *(const short8*)&A2[(mt * 16 + lm) * KP + ks * 32 + quad * 8];
            #pragma unroll
            for (int mt = 0; mt < 2; ++mt)
                #pragma unroll
                for (int nt = 0; nt < 4; ++nt)
                    c1[mt][nt] = __builtin_amdgcn_mfma_f32_16x16x32_bf16(a[mt], bcur[nt], c1[mt][nt], 0, 0, 0);
            #pragma unroll
            for (int nt = 0; nt < 4; ++nt) bcur[nt] = bnxt[nt];
        }
    }
    __syncthreads();            // barrier 2 (all reads of A/A2 done)
    // write relu(u_pre) -> A
    #pragma unroll
    for (int mt = 0; mt < 2; ++mt)
        #pragma unroll
        for (int nt = 0; nt < 4; ++nt) {
            int col = ncol + nt * 16;
            #pragma unroll
            for (int r = 0; r < 4; ++r) {
                int row = mt * 16 + quad * 4 + r;
                A[row * KP + col] = f2bf(fmaxf(c1[mt][nt][r], 0.f));
            }
        }
    __syncthreads();            // barrier 3

    // --- stage 3: GEMM K=256 @W2 + b2 + residual; LN; store ---
    floatx4 c3[2][4];
    #pragma unroll
    for (int nt = 0; nt < 4; ++nt) {
        float bb = b2[ncol + nt * 16];
        #pragma unroll
        for (int mt = 0; mt < 2; ++mt) {
            c3[mt][nt][0] = bb; c3[mt][nt][1] = bb;
            c3[mt][nt][2] = bb; c3[mt][nt][3] = bb;
        }
    }
    {
        short8 bcur[4], bnxt[4];
        #pragma unroll
        for (int nt = 0; nt < 4; ++nt)
            bcur[nt] = *(const short8*)&u2bt[(size_t)(ncol + nt * 16) * H + quad * 8];
        #pragma unroll
        for (int ks = 0; ks < 8; ++ks) {
            if (ks < 7) {
                #pragma unroll
                for (int nt = 0; nt < 4; ++nt)
                    bnxt[nt] = *(const short8*)&u2bt[(size_t)(ncol + nt * 16) * H + (ks + 1) * 32 + quad * 8];
            }
            short8 a[2];
            #pragma unroll
            for (int mt = 0; mt < 2; ++mt)
                a[mt] = *(const short8*)&A[(mt * 16 + lm) * KP + ks * 32 + quad * 8];
            #pragma unroll
            for (int mt = 0; mt < 2; ++mt)
                #pragma unroll
                for (int nt = 0; nt < 4; ++nt)
                    c3[mt][nt] = __builtin_amdgcn_mfma_f32_16x16x32_bf16(a[mt], bcur[nt], c3[mt][nt], 0, 0, 0);
            #pragma unroll
            for (int nt = 0; nt < 4; ++nt) bcur[nt] = bnxt[nt];
        }
    }
    #pragma unroll
    for (int mt = 0; mt < 2; ++mt)
        #pragma unroll
        for (int r = 0; r < 4; ++r) {
            int row = mt * 16 + quad * 4 + r;
            if (row < nvalid) {
                #pragma unroll
                for (int nt = 0; nt < 4; ++nt)
                    c3[mt][nt][r] += bf2f(h_in_bf[(size_t)(n0 + row) * H + ncol + nt * 16]);
            }
        }

    // LN partials
    #pragma unroll
    for (int mt = 0; mt < 2; ++mt)
        #pragma unroll
        for (int r = 0; r < 4; ++r) {
            float s = 0.f, q = 0.f;
            #pragma unroll
            for (int nt = 0; nt < 4; ++nt) {
                float v = c3[mt][nt][r];
                s += v; q += v * v;
            }
            #pragma unroll
            for (int m = 1; m < 16; m <<= 1) {
                s += __shfl_xor(s, m, 64);
                q += __shfl_xor(q, m, 64);
            }
            if (lm == 0) {
                int row = mt * 16 + quad * 4 + r;
                psum[row][wave] = s;
                psq[row][wave]  = q;
            }
        }
    __syncthreads();            // barrier 4
    if (tid < M) {
        float s = psum[tid][0] + psum[tid][1] + psum[tid][2] + psum[tid][3];
        float q = psq[tid][0] + psq[tid][1] + psq[tid][2] + psq[tid][3];
        float mu = s * (1.f / H);
        float var = q * (1.f / H) - mu * mu;
        muS[tid] = mu;
        rsS[tid] = rsqrtf(fmaxf(var, 0.f) + 1e-5f);
    }
    __syncthreads();            // barrier 5

    float g[4], bb4[4];
    #pragma unroll
    for (int nt = 0; nt < 4; ++nt) {
        g[nt]   = lng[ncol + nt * 16];
        bb4[nt] = lnb[ncol + nt * 16];
    }
    const bool wbf = (h_out_bf != nullptr);
    const bool wf  = (h_out_f32 != nullptr);
    #pragma unroll
    for (int mt = 0; mt < 2; ++mt)
        #pragma unroll
        for (int r = 0; r < 4; ++r) {
            int row = mt * 16 + quad * 4 + r;
            if (row < nvalid) {
                float mu = muS[row], rsv = rsS[row];
                #pragma unroll
                for (int nt = 0; nt < 4; ++nt) {
                    float o = (c3[mt][nt][r] - mu) * rsv * g[nt] + bb4[nt];
                    size_t off = (size_t)(n0 + row) * H + ncol + nt * 16;
                    if (wbf) h_out_bf[off] = f2bf(o);
                    if (wf)  h_out_f32[off] = o;
                }
            }
        }
}

// ---------------------------------------------------------------------------
// Pooling (batch sorted -> LDS accumulate, flush on change)
// ---------------------------------------------------------------------------
__global__ __launch_bounds__(256) void pool_kernel(
    const float* __restrict__ h, const int* __restrict__ batch,
    const int* __restrict__ ntype,
    float* __restrict__ zsum, float* __restrict__ zcnt)
{
    constexpr int CHUNK = 256;
    __shared__ float acc[3][H];
    __shared__ float cnt[3];
    const int tid = threadIdx.x;
    const int n0 = blockIdx.x * CHUNK;
    const int nend = min(n0 + CHUNK, N);

    for (int q = 0; q < 3; ++q) acc[q][tid] = 0.f;
    if (tid == 0) { cnt[0] = 0.f; cnt[1] = 0.f; cnt[2] = 0.f; }
    __syncthreads();

    int cur = batch[n0];
    for (int n = n0; n < nend; ++n) {
        int b = batch[n];
        int t = ntype[n];
        if (b != cur) {
            for (int q = 0; q < 3; ++q) {
                atomicAdd(&zsum[cur * (3 * H) + q * H + tid], acc[q][tid]);
                acc[q][tid] = 0.f;
            }
            if (tid == 0)
                for (int q = 0; q < 3; ++q) { atomicAdd(&zcnt[cur * 3 + q], cnt[q]); cnt[q] = 0.f; }
            cur = b;
        }
        acc[t][tid] += h[(size_t)n * H + tid];
        if (tid == 0) cnt[t] += 1.f;
    }
    for (int q = 0; q < 3; ++q)
        atomicAdd(&zsum[cur * (3 * H) + q * H + tid], acc[q][tid]);
    if (tid == 0)
        for (int q = 0; q < 3; ++q) atomicAdd(&zcnt[cur * 3 + q], cnt[q]);
}

__global__ __launch_bounds__(256) void finalize_kernel(
    const float* __restrict__ zsum, const float* __restrict__ zcnt,
    float* __restrict__ out)
{
    int idx = blockIdx.x * 256 + threadIdx.x;
    if (idx >= B * 3 * H) return;
    int b = idx / (3 * H);
    int c = idx % (3 * H);
    int t = c / H;
    float cn = zcnt[b * 3 + t];
    out[idx] = zsum[idx] / fmaxf(cn, 1.f);
}

__global__ __launch_bounds__(256) void batch_out_kernel(
    const int* __restrict__ batch, float* __restrict__ out)
{
    int idx = blockIdx.x * 256 + threadIdx.x;
    if (idx < N) out[idx] = (float)batch[idx];
}

// ---------------------------------------------------------------------------
extern "C" void kernel_launch(void* const* d_in, const int* in_sizes, int n_in,
                              void* d_out, int out_size, void* d_ws, size_t ws_size,
                              hipStream_t stream) {
    const float* x         = (const float*)d_in[0];
    const float* edge_attr = (const float*)d_in[1];
    const float* geo_w     = (const float*)d_in[2];
    const float* geo_b     = (const float*)d_in[3];
    const float* nin_w1    = (const float*)d_in[4];
    const float* nin_b1    = (const float*)d_in[5];
    const float* nin_w2    = (const float*)d_in[6];
    const float* nin_b2    = (const float*)d_in[7];
    const float* ee_w1     = (const float*)d_in[8];
    const float* ee_b1     = (const float*)d_in[9];
    const float* ee_w2     = (const float*)d_in[10];
    const float* ee_b2     = (const float*)d_in[11];
    const float* msgx_w    = (const float*)d_in[12];
    const float* msge_w    = (const float*)d_in[13];
    const float* upd_w1    = (const float*)d_in[14];
    const float* upd_b1    = (const float*)d_in[15];
    const float* upd_w2    = (const float*)d_in[16];
    const float* upd_b2    = (const float*)d_in[17];
    const float* ln_g      = (const float*)d_in[18];
    const float* ln_b      = (const float*)d_in[19];
    const int*   edge_index= (const int*)d_in[20];
    const int*   batch     = (const int*)d_in[21];
    const int*   node_type = (const int*)d_in[22];

    float* out = (float*)d_out;
    float* hf  = out + B * 3 * H;                  // final f32 h -> d_out

    // Workspace layout (~104 MB):
    short* h0_bf   = (short*)d_ws;                     // [N,H] bf16  25.6 MB
    short* h1_bf   = h0_bf + (size_t)N * H;            // [N,H] bf16  25.6 MB
    short* haggB   = h1_bf + (size_t)N * H;            // [N,H] bf16  25.6 MB
    short* fusedT  = haggB + (size_t)N * H;            // [L,H,512] bf16 (F1|F2)
    short* u2bt    = fusedT + (size_t)L * H * 512;     // [L,H,H] bf16
    short* geowbt  = u2bt + (size_t)L * H * H;         // [32,128]
    short* w1bt    = geowbt + 32 * 128;                // [H,64]
    short* w2bt    = w1bt + H * 64;                    // [H,H]
    short* ew1T    = w2bt + H * H;                     // [256,32] bf16 K-padded
    float* WEf32   = (float*)(ew1T + 256 * 32);        // [L,H,H] f32 (4 MB)
    float* be2     = WEf32 + (size_t)L * H * H;        // [L,H]
    float* be2w1   = be2 + L * H;                      // [L,H]
    float* zsum    = be2w1 + L * H;                    // [B,3H]
    float* zcnt    = zsum + B * 3 * H;                 // [B,3]
    int*   rowcnt  = (int*)(zcnt + B * 3);             // [N]
    int*   rs      = rowcnt + N;                       // [N+1]
    int*   cursor  = rs + N + 1;                       // [N]
    int*   bsum    = cursor + N;                       // [256]
    int*   csr_src = bsum + 256;                       // [E]
    float* ea_csr  = (float*)(csr_src + E);            // [E,ED] f32 19.2 MB

    const int* src = edge_index;
    const int* dst = edge_index + E;

    const int nscan = (N + 255) / 256;   // 196 blocks <= 256

    // --- CSR build (+ edge-attr reorder) ---
    hipMemsetAsync(rowcnt, 0, (size_t)N * sizeof(int), stream);
    hist_kernel<<<(E + 255) / 256, 256, 0, stream>>>(dst, rowcnt);
    scan_partial_kernel<<<nscan, 256, 0, stream>>>(rowcnt, bsum);
    scan_bsum_kernel<<<1, 256, 0, stream>>>(bsum, nscan, rs + N);
    scan_final_kernel<<<nscan, 256, 0, stream>>>(rowcnt, bsum, rs, cursor);
    fill_kernel<<<(E + 255) / 256, 256, 0, stream>>>(src, dst, edge_attr, cursor, csr_src, ea_csr);

    // --- weight prep (fused weights) ---
    we_fuse_kernel<<<L * H, 256, 0, stream>>>(ee_w2, msge_w, WEf32);
    fuse1_kernel<<<L * H, 256, 0, stream>>>(msgx_w, upd_w1, fusedT);
    fuse2_kernel<<<L * H, 256, 0, stream>>>(WEf32, upd_w1, fusedT);
    fuse_b_kernel<<<L, 256, 0, stream>>>(ee_b2, msge_w, be2);
    fuse_bias_kernel<<<L, 256, 0, stream>>>(be2, upd_w1, be2w1);
    conv_bt_kernel<<<L * 256, 256, 0, stream>>>(upd_w2, u2bt);
    conv_bt_kernel<<<256, 256, 0, stream>>>(nin_w2, w2bt);
    geow_bt_kernel<<<1, 256, 0, stream>>>(geo_w, geowbt);
    ninw1_bt_kernel<<<64, 256, 0, stream>>>(nin_w1, w1bt);
    ew1t_kernel<<<1, 256, 0, stream>>>(ee_w1, ew1T);

    // --- hiddenAgg (layer-independent): MFMA over CSR-contiguous edges ---
    hidden_agg_mfma_kernel<<<(N + 31) / 32, 256, 0, stream>>>(
        ea_csr, ew1T, ee_b1, rs, haggB);

    // --- node encoder -> h0_bf ---
    node_in_mfma_kernel<<<(N + 63) / 64, 256, 0, stream>>>(
        x, geowbt, geo_b, w1bt, nin_b1, w2bt, nin_b2, h0_bf);

    // --- layers: bf16 ping-pong; gather writes into the out buffer (safe:
    // each layer block reads only its own rows, then overwrites them) ---
    const int lgrid = (N + 31) / 32;
    for (int l = 0; l < L; ++l) {
        const short* hin  = (l & 1) ? h1_bf : h0_bf;
        short* aggb       = (l & 1) ? h0_bf : h1_bf;   // out ping-pong buffer
        short* hout_bf    = (l == L - 1) ? nullptr : aggb;
        float* hout_f32   = (l == L - 1) ? hf : nullptr;
        gather_kernel<<<(N + 3) / 4, 256, 0, stream>>>(hin, rs, csr_src, aggb);
        layer_kernel<<<lgrid, 256, 0, stream>>>(
            hin, hout_bf, hout_f32, aggb, rs, haggB,
            fusedT + (size_t)l * H * 512, be2w1 + (size_t)l * H,
            upd_b1 + (size_t)l * H,
            u2bt + (size_t)l * H * H, upd_b2 + (size_t)l * H,
            ln_g + (size_t)l * H, ln_b + (size_t)l * H);
    }

    // --- pooling ---
    hipMemsetAsync(zsum, 0, (size_t)(B * 3 * H + B * 3) * sizeof(float), stream);
    pool_kernel<<<(N + 255) / 256, 256, 0, stream>>>(hf, batch, node_type, zsum, zcnt);
    finalize_kernel<<<(B * 3 * H + 255) / 256, 256, 0, stream>>>(zsum, zcnt, out);
    batch_out_kernel<<<(N + 255) / 256, 256, 0, stream>>>(batch, out + B * 3 * H + (size_t)N * H);
}

// Round 13
// 916.457 us; speedup vs baseline: 1.2678x; 1.0021x over previous
//
#include <hip/hip_runtime.h>

// Problem constants (from reference)
constexpr int N  = 50000;
constexpr int E  = 300000;
constexpr int B  = 8;
constexpr int XD = 160;
constexpr int ED = 16;
constexpr int H  = 256;
constexpr int L  = 4;
constexpr int G  = 32;

typedef __attribute__((ext_vector_type(8))) short short8;
typedef __attribute__((ext_vector_type(4))) short sv4;
typedef __attribute__((ext_vector_type(4))) float floatx4;

// f32 -> bf16 round-to-nearest-even
__device__ __forceinline__ short f2bf(float f) {
    union { float f; unsigned u; } v; v.f = f;
    unsigned r = (v.u + 0x7fffu + ((v.u >> 16) & 1u)) >> 16;
    return (short)r;
}
__device__ __forceinline__ float bf2f(short s) {
    union { unsigned u; float f; } v;
    v.u = ((unsigned)(unsigned short)s) << 16;
    return v.f;
}

// ---------------------------------------------------------------------------
// CSR build: histogram, 3-pass multi-block scan, fill (+ edge-attr reorder)
// ---------------------------------------------------------------------------
__global__ __launch_bounds__(256) void hist_kernel(
    const int* __restrict__ dst, int* __restrict__ cnt)
{
    int e = blockIdx.x * 256 + threadIdx.x;
    if (e < E) atomicAdd(&cnt[dst[e]], 1);
}

__global__ __launch_bounds__(256) void scan_partial_kernel(
    const int* __restrict__ cnt, int* __restrict__ bsum)
{
    __shared__ int s[256];
    const int tid = threadIdx.x;
    int i = blockIdx.x * 256 + tid;
    s[tid] = (i < N) ? cnt[i] : 0;
    __syncthreads();
    #pragma unroll
    for (int off = 128; off > 0; off >>= 1) {
        if (tid < off) s[tid] += s[tid + off];
        __syncthreads();
    }
    if (tid == 0) bsum[blockIdx.x] = s[0];
}

__global__ __launch_bounds__(256) void scan_bsum_kernel(
    int* __restrict__ bsum, int nb, int* __restrict__ rsN)
{
    __shared__ int s[256];
    const int tid = threadIdx.x;
    int v = (tid < nb) ? bsum[tid] : 0;
    s[tid] = v;
    __syncthreads();
    #pragma unroll
    for (int off = 1; off < 256; off <<= 1) {
        int x = (tid >= off) ? s[tid - off] : 0;
        __syncthreads();
        s[tid] += x;
        __syncthreads();
    }
    if (tid < nb) bsum[tid] = s[tid] - v;
    if (tid == 255) *rsN = s[255];
}

__global__ __launch_bounds__(256) void scan_final_kernel(
    const int* __restrict__ cnt, const int* __restrict__ bsum,
    int* __restrict__ rs, int* __restrict__ cursor)
{
    __shared__ int s[256];
    const int tid = threadIdx.x;
    int i = blockIdx.x * 256 + tid;
    int v = (i < N) ? cnt[i] : 0;
    s[tid] = v;
    __syncthreads();
    #pragma unroll
    for (int off = 1; off < 256; off <<= 1) {
        int x = (tid >= off) ? s[tid - off] : 0;
        __syncthreads();
        s[tid] += x;
        __syncthreads();
    }
    int excl = s[tid] - v + bsum[blockIdx.x];
    if (i < N) { rs[i] = excl; cursor[i] = excl; }
}

// fill + CSR-reorder of edge attrs: ea_csr[pos] = ea[e].
__global__ __launch_bounds__(256) void fill_kernel(
    const int* __restrict__ src, const int* __restrict__ dst,
    const float* __restrict__ ea,
    int* __restrict__ cursor, int* __restrict__ csr_src,
    float* __restrict__ ea_csr)
{
    int e = blockIdx.x * 256 + threadIdx.x;
    if (e < E) {
        int d = dst[e];
        int pos = atomicAdd(&cursor[d], 1);
        csr_src[pos] = src[e];
        const float4* a = (const float4*)(ea + (size_t)e * ED);
        float4* o = (float4*)(ea_csr + (size_t)pos * ED);
        o[0] = a[0]; o[1] = a[1]; o[2] = a[2]; o[3] = a[3];
    }
}

// ---------------------------------------------------------------------------
// hiddenAgg via MFMA: per block, 32 nodes; loop 64-edge windows of the
// CSR-contiguous edge range.
//   GEMM1: R = relu(EA @ W + b)           (edges x 256, K=32 zero-padded)
//   GEMM2: hagg += S @ R                   (nodes x 256, K=64)
// ---------------------------------------------------------------------------
__global__ __launch_bounds__(256, 3) void hidden_agg_mfma_kernel(
    const float* __restrict__ ea_csr,
    const short* __restrict__ ew1T, const float* __restrict__ eb1,
    const int* __restrict__ rs,
    short* __restrict__ haggB)
{
    __shared__ short EA[64 * 32];      // [edge][k] bf16, k 16..31 zero
    __shared__ short RT[256 * 68];     // [col][edge] bf16
    __shared__ short S [32 * 68];      // [node][edge] bf16 0/1
    __shared__ int rsL[33];
    const int tid  = threadIdx.x;
    const int lane = tid & 63, wave = tid >> 6;
    const int quad = lane >> 4, lm = lane & 15;
    const int n0 = blockIdx.x * 32;
    const int nvalid = min(32, N - n0);
    const int ncol = wave * 64 + lm;

    if (tid < 33) rsL[tid] = rs[min(n0 + tid, N)];
    for (int i = tid; i < 64 * 16; i += 256) {
        int row = i >> 4, k = i & 15;
        EA[row * 32 + 16 + k] = 0;
    }

    short8 wf[4];
    float ebv[4];
    #pragma unroll
    for (int nt = 0; nt < 4; ++nt) {
        wf[nt]  = *(const short8*)&ew1T[(size_t)(ncol + nt * 16) * 32 + quad * 8];
        ebv[nt] = eb1[ncol + nt * 16];
    }
    __syncthreads();

    const int e_start = rsL[0], e_end = rsL[32];

    floatx4 c2[2][4];
    #pragma unroll
    for (int mt = 0; mt < 2; ++mt)
        #pragma unroll
        for (int nt = 0; nt < 4; ++nt)
            c2[mt][nt] = {0.f, 0.f, 0.f, 0.f};

    for (int w0 = e_start; w0 < e_end; w0 += 64) {
        for (int i = tid; i < 64 * 16; i += 256) {
            int row = i >> 4, k = i & 15;
            int e = w0 + row;
            float v = (e < e_end) ? ea_csr[(size_t)e * ED + k] : 0.f;
            EA[row * 32 + k] = f2bf(v);
        }
        for (int i = tid; i < 32 * 64; i += 256) {
            int nd = i >> 6, el = i & 63;
            int e = w0 + el;
            S[nd * 68 + el] = (e >= rsL[nd] && e < rsL[nd + 1]) ? (short)0x3F80 : (short)0;
        }
        __syncthreads();

        floatx4 c1[4][4];
        #pragma unroll
        for (int nt = 0; nt < 4; ++nt)
            #pragma unroll
            for (int mt = 0; mt < 4; ++mt) {
                c1[mt][nt][0] = ebv[nt]; c1[mt][nt][1] = ebv[nt];
                c1[mt][nt][2] = ebv[nt]; c1[mt][nt][3] = ebv[nt];
            }
        short8 a[4];
        #pragma unroll
        for (int mt = 0; mt < 4; ++mt)
            a[mt] = *(const short8*)&EA[(mt * 16 + lm) * 32 + quad * 8];
        #pragma unroll
        for (int mt = 0; mt < 4; ++mt)
            #pragma unroll
            for (int nt = 0; nt < 4; ++nt)
                c1[mt][nt] = __builtin_amdgcn_mfma_f32_16x16x32_bf16(a[mt], wf[nt], c1[mt][nt], 0, 0, 0);
        #pragma unroll
        for (int mt = 0; mt < 4; ++mt)
            #pragma unroll
            for (int nt = 0; nt < 4; ++nt) {
                sv4 o = {f2bf(fmaxf(c1[mt][nt][0], 0.f)), f2bf(fmaxf(c1[mt][nt][1], 0.f)),
                         f2bf(fmaxf(c1[mt][nt][2], 0.f)), f2bf(fmaxf(c1[mt][nt][3], 0.f))};
                *(sv4*)&RT[(ncol + nt * 16) * 68 + mt * 16 + quad * 4] = o;
            }
        __syncthreads();

        #pragma unroll
        for (int ks = 0; ks < 2; ++ks) {
            short8 a2[2], b2[4];
            #pragma unroll
            for (int mt = 0; mt < 2; ++mt)
                a2[mt] = *(const short8*)&S[(mt * 16 + lm) * 68 + ks * 32 + quad * 8];
            #pragma unroll
            for (int nt = 0; nt < 4; ++nt)
                b2[nt] = *(const short8*)&RT[(ncol + nt * 16) * 68 + ks * 32 + quad * 8];
            #pragma unroll
            for (int mt = 0; mt < 2; ++mt)
                #pragma unroll
                for (int nt = 0; nt < 4; ++nt)
                    c2[mt][nt] = __builtin_amdgcn_mfma_f32_16x16x32_bf16(a2[mt], b2[nt], c2[mt][nt], 0, 0, 0);
        }
        __syncthreads();
    }

    #pragma unroll
    for (int mt = 0; mt < 2; ++mt)
        #pragma unroll
        for (int r = 0; r < 4; ++r) {
            int row = mt * 16 + quad * 4 + r;
            if (row < nvalid) {
                #pragma unroll
                for (int nt = 0; nt < 4; ++nt)
                    haggB[(size_t)(n0 + row) * H + ncol + nt * 16] = f2bf(c2[mt][nt][r]);
            }
        }
}

// ---------------------------------------------------------------------------
// Neighbor gather: agg_bf[n] = bf16( sum_{e: dst=n} h_in_bf[src_e] )
// One node per wave; 16B/lane (short8), 32 lanes per row -> each vector load
// fetches TWO neighbor rows (one per half-wave). Halves combine via one
// shfl_xor(32) pass; lanes 0..31 write 16B each.
// ---------------------------------------------------------------------------
__global__ __launch_bounds__(256) void gather_kernel(
    const short* __restrict__ h_in_bf,
    const int* __restrict__ rs, const int* __restrict__ csr_src,
    short* __restrict__ agg_bf)
{
    const int lane = threadIdx.x & 63;
    const int wave = threadIdx.x >> 6;
    const int half = lane >> 5;          // 0 or 1: which edge of the pair
    const int l32  = lane & 31;          // 16B column group
    const int n = blockIdx.x * 4 + wave;
    if (n >= N) return;
    const int s = rs[n], e = rs[n + 1];
    float acc[8] = {0.f, 0.f, 0.f, 0.f, 0.f, 0.f, 0.f, 0.f};
    int j = s;
    // 4 edges per iteration: two 2-edge vector loads
    for (; j + 4 <= e; j += 4) {
        const int e0 = csr_src[j + half];
        const int e1 = csr_src[j + 2 + half];
        short8 v0 = *(const short8*)&h_in_bf[(size_t)e0 * H + 8 * l32];
        short8 v1 = *(const short8*)&h_in_bf[(size_t)e1 * H + 8 * l32];
        #pragma unroll
        for (int q = 0; q < 8; ++q)
            acc[q] += bf2f(v0[q]) + bf2f(v1[q]);
    }
    if (j + 2 <= e) {
        const int e0 = csr_src[j + half];
        short8 v0 = *(const short8*)&h_in_bf[(size_t)e0 * H + 8 * l32];
        #pragma unroll
        for (int q = 0; q < 8; ++q)
            acc[q] += bf2f(v0[q]);
        j += 2;
    }
    if (j < e && half == 0) {
        const int e0 = csr_src[j];
        short8 v0 = *(const short8*)&h_in_bf[(size_t)e0 * H + 8 * l32];
        #pragma unroll
        for (int q = 0; q < 8; ++q)
            acc[q] += bf2f(v0[q]);
    }
    // combine even-edge and odd-edge partial sums (lane l <-> l+32)
    #pragma unroll
    for (int q = 0; q < 8; ++q)
        acc[q] += __shfl_xor(acc[q], 32, 64);
    if (half == 0) {
        short8 o;
        #pragma unroll
        for (int q = 0; q < 8; ++q) o[q] = f2bf(acc[q]);
        *(short8*)&agg_bf[(size_t)n * H + 8 * l32] = o;
    }
}

// ---------------------------------------------------------------------------
// Weight prep. Algebraic fusion: u = relu( agg@(Wx.W1) + hagg@(We'.W1)
//                                         + deg*(be2.W1) + b1 )
// ---------------------------------------------------------------------------
__global__ __launch_bounds__(256) void we_fuse_kernel(
    const float* __restrict__ ee_w2, const float* __restrict__ msge_w,
    float* __restrict__ WEf32)
{
    __shared__ float wrow[H];
    const int tid = threadIdx.x;
    const int l = blockIdx.x / H;
    const int t = blockIdx.x % H;
    wrow[tid] = ee_w2[t * H + tid];
    __syncthreads();
    const float* mw = msge_w + (size_t)l * H * H;
    float acc = 0.f;
    for (int k = 0; k < H; ++k)
        acc += wrow[k] * mw[k * H + tid];
    WEf32[((size_t)l * H + t) * H + tid] = acc;
}

__global__ __launch_bounds__(256) void fuse1_kernel(
    const float* __restrict__ msgx_w, const float* __restrict__ upd_w1,
    short* __restrict__ fusedT)
{
    __shared__ float wrow[H];
    const int tid = threadIdx.x;
    const int l = blockIdx.x / H;
    const int t = blockIdx.x % H;
    wrow[tid] = msgx_w[((size_t)l * H + t) * H + tid];
    __syncthreads();
    const float* w1 = upd_w1 + (size_t)l * H * H;
    float acc = 0.f;
    for (int j = 0; j < H; ++j)
        acc += wrow[j] * w1[j * H + tid];
    fusedT[((size_t)(l * H + tid)) * 512 + t] = f2bf(acc);
}

__global__ __launch_bounds__(256) void fuse2_kernel(
    const float* __restrict__ WEf32, const float* __restrict__ upd_w1,
    short* __restrict__ fusedT)
{
    __shared__ float wrow[H];
    const int tid = threadIdx.x;
    const int l = blockIdx.x / H;
    const int t = blockIdx.x % H;
    wrow[tid] = WEf32[((size_t)l * H + t) * H + tid];
    __syncthreads();
    const float* w1 = upd_w1 + (size_t)l * H * H;
    float acc = 0.f;
    for (int j = 0; j < H; ++j)
        acc += wrow[j] * w1[j * H + tid];
    fusedT[((size_t)(l * H + tid)) * 512 + 256 + t] = f2bf(acc);
}

__global__ __launch_bounds__(256) void fuse_b_kernel(
    const float* __restrict__ ee_b2, const float* __restrict__ msge_w,
    float* __restrict__ be2)
{
    __shared__ float brow[H];
    const int tid = threadIdx.x;
    const int l = blockIdx.x;
    brow[tid] = ee_b2[tid];
    __syncthreads();
    const float* mw = msge_w + (size_t)l * H * H;
    float acc = 0.f;
    for (int k = 0; k < H; ++k)
        acc += brow[k] * mw[k * H + tid];
    be2[l * H + tid] = acc;
}

__global__ __launch_bounds__(256) void fuse_bias_kernel(
    const float* __restrict__ be2, const float* __restrict__ upd_w1,
    float* __restrict__ be2w1)
{
    __shared__ float brow[H];
    const int tid = threadIdx.x;
    const int l = blockIdx.x;
    brow[tid] = be2[l * H + tid];
    __syncthreads();
    const float* w1 = upd_w1 + (size_t)l * H * H;
    float acc = 0.f;
    for (int j = 0; j < H; ++j)
        acc += brow[j] * w1[j * H + tid];
    be2w1[l * H + tid] = acc;
}

__global__ __launch_bounds__(256) void conv_bt_kernel(
    const float* __restrict__ w, short* __restrict__ bt)
{
    int mat = blockIdx.x >> 8, k = blockIdx.x & 255, n = threadIdx.x;
    bt[((size_t)mat * H + n) * H + k] = f2bf(w[((size_t)mat * H + k) * H + n]);
}

__global__ __launch_bounds__(256) void geow_bt_kernel(
    const float* __restrict__ w, short* __restrict__ bt)
{
    for (int i = threadIdx.x; i < 32 * 128; i += 256) {
        int n = i >> 7, k = i & 127;
        bt[i] = f2bf(w[k * 32 + n]);
    }
}

__global__ __launch_bounds__(256) void ninw1_bt_kernel(
    const float* __restrict__ w, short* __restrict__ bt)
{
    int i = blockIdx.x * 256 + threadIdx.x;
    int n = i >> 6, k = i & 63;
    bt[i] = f2bf(w[k * H + n]);
}

// ew1T[col][k] = bf16(ew1[k][col]) for k<16, 0 for k in 16..31 (K-pad)
__global__ __launch_bounds__(256) void ew1t_kernel(
    const float* __restrict__ ew1, short* __restrict__ ew1T)
{
    int t = threadIdx.x;
    #pragma unroll
    for (int k = 0; k < ED; ++k)
        ew1T[t * 32 + k] = f2bf(ew1[k * H + t]);
    #pragma unroll
    for (int k = ED; k < 32; ++k)
        ew1T[t * 32 + k] = 0;
}

// ---------------------------------------------------------------------------
// Node input encoder (MFMA). M=64 nodes/block. Writes h_bf (bf16 only).
// ---------------------------------------------------------------------------
__global__ __launch_bounds__(256) void node_in_mfma_kernel(
    const float* __restrict__ x,
    const short* __restrict__ geo_wbt, const float* __restrict__ geo_b,
    const short* __restrict__ w1bt, const float* __restrict__ b1,
    const short* __restrict__ w2bt, const float* __restrict__ b2,
    short* __restrict__ h_bf)
{
    constexpr int KP = H + 8;
    constexpr int KX = 128 + 8;
    constexpr int KI = 64 + 8;
    __shared__ short A[64 * KP];
    __shared__ short XIN[64 * KI];
    const int tid = threadIdx.x;
    const int lane = tid & 63, wave = tid >> 6;
    const int quad = lane >> 4, lm = lane & 15;
    const int n0 = blockIdx.x * 64;
    const int nvalid = min(64, N - n0);
    const int ncol = wave * 64 + lm;

    for (int i = tid; i < 64 * 128; i += 256) {
        int row = i >> 7, k = i & 127;
        float v = (row < nvalid) ? x[(size_t)(n0 + row) * XD + k] : 0.f;
        A[row * KX + k] = f2bf(v);
    }
    for (int i = tid; i < 64 * 32; i += 256) {
        int row = i >> 5, k = i & 31;
        float v = (row < nvalid) ? x[(size_t)(n0 + row) * XD + 128 + k] : 0.f;
        XIN[row * KI + 32 + k] = f2bf(v);
    }
    __syncthreads();

    // geo GEMM
    {
        floatx4 c[2];
        float b0 = geo_b[lm], b1v = geo_b[16 + lm];
        c[0] = {b0, b0, b0, b0};
        c[1] = {b1v, b1v, b1v, b1v};
        #pragma unroll
        for (int ks = 0; ks < 4; ++ks) {
            short8 a  = *(const short8*)&A[(wave * 16 + lm) * KX + ks * 32 + quad * 8];
            short8 w0 = *(const short8*)&geo_wbt[(size_t)lm * 128 + ks * 32 + quad * 8];
            short8 w1 = *(const short8*)&geo_wbt[(size_t)(16 + lm) * 128 + ks * 32 + quad * 8];
            c[0] = __builtin_amdgcn_mfma_f32_16x16x32_bf16(a, w0, c[0], 0, 0, 0);
            c[1] = __builtin_amdgcn_mfma_f32_16x16x32_bf16(a, w1, c[1], 0, 0, 0);
        }
        #pragma unroll
        for (int nt = 0; nt < 2; ++nt)
            #pragma unroll
            for (int r = 0; r < 4; ++r) {
                int row = wave * 16 + quad * 4 + r;
                XIN[row * KI + nt * 16 + lm] = f2bf(fmaxf(c[nt][r], 0.f));
            }
    }
    __syncthreads();

    // GEMM1: K=64 -> hid (relu) into A
    floatx4 c1[4][4];
    #pragma unroll
    for (int nt = 0; nt < 4; ++nt) {
        float bb = b1[ncol + nt * 16];
        #pragma unroll
        for (int mt = 0; mt < 4; ++mt) {
            c1[mt][nt][0] = bb; c1[mt][nt][1] = bb;
            c1[mt][nt][2] = bb; c1[mt][nt][3] = bb;
        }
    }
    #pragma unroll
    for (int ks = 0; ks < 2; ++ks) {
        short8 a[4], b[4];
        #pragma unroll
        for (int mt = 0; mt < 4; ++mt)
            a[mt] = *(const short8*)&XIN[(mt * 16 + lm) * KI + ks * 32 + quad * 8];
        #pragma unroll
        for (int nt = 0; nt < 4; ++nt)
            b[nt] = *(const short8*)&w1bt[(size_t)(ncol + nt * 16) * 64 + ks * 32 + quad * 8];
        #pragma unroll
        for (int mt = 0; mt < 4; ++mt)
            #pragma unroll
            for (int nt = 0; nt < 4; ++nt)
                c1[mt][nt] = __builtin_amdgcn_mfma_f32_16x16x32_bf16(a[mt], b[nt], c1[mt][nt], 0, 0, 0);
    }
    __syncthreads();
    #pragma unroll
    for (int mt = 0; mt < 4; ++mt)
        #pragma unroll
        for (int nt = 0; nt < 4; ++nt) {
            int col = ncol + nt * 16;
            #pragma unroll
            for (int r = 0; r < 4; ++r) {
                int row = mt * 16 + quad * 4 + r;
                A[row * KP + col] = f2bf(fmaxf(c1[mt][nt][r], 0.f));
            }
        }
    __syncthreads();

    // GEMM2: K=256 -> h_bf
    floatx4 c2[4][4];
    #pragma unroll
    for (int nt = 0; nt < 4; ++nt) {
        float bb = b2[ncol + nt * 16];
        #pragma unroll
        for (int mt = 0; mt < 4; ++mt) {
            c2[mt][nt][0] = bb; c2[mt][nt][1] = bb;
            c2[mt][nt][2] = bb; c2[mt][nt][3] = bb;
        }
    }
    #pragma unroll
    for (int ks = 0; ks < 8; ++ks) {
        short8 a[4], b[4];
        #pragma unroll
        for (int mt = 0; mt < 4; ++mt)
            a[mt] = *(const short8*)&A[(mt * 16 + lm) * KP + ks * 32 + quad * 8];
        #pragma unroll
        for (int nt = 0; nt < 4; ++nt)
            b[nt] = *(const short8*)&w2bt[(size_t)(ncol + nt * 16) * H + ks * 32 + quad * 8];
        #pragma unroll
        for (int mt = 0; mt < 4; ++mt)
            #pragma unroll
            for (int nt = 0; nt < 4; ++nt)
                c2[mt][nt] = __builtin_amdgcn_mfma_f32_16x16x32_bf16(a[mt], b[nt], c2[mt][nt], 0, 0, 0);
    }
    #pragma unroll
    for (int mt = 0; mt < 4; ++mt)
        #pragma unroll
        for (int r = 0; r < 4; ++r) {
            int row = mt * 16 + quad * 4 + r;
            if (row < nvalid) {
                #pragma unroll
                for (int nt = 0; nt < 4; ++nt)
                    h_bf[(size_t)(n0 + row) * H + ncol + nt * 16] = f2bf(c2[mt][nt][r]);
            }
        }
}

// ---------------------------------------------------------------------------
// Fused layer kernel, M=32 nodes/block, 3 GEMM passes.
// NOTE: agg_bf aliases the output ping-pong buffer: each block reads only its
// own 32 rows (stage 1) and overwrites exactly those rows at the end.
// ---------------------------------------------------------------------------
__global__ __launch_bounds__(256, 4) void layer_kernel(
    const short* __restrict__ h_in_bf, short* __restrict__ h_out_bf,
    float* __restrict__ h_out_f32,
    const short* __restrict__ agg_bf,
    const int* __restrict__ rs,
    const short* __restrict__ haggB,
    const short* __restrict__ fusedT, const float* __restrict__ be2w1,
    const float* __restrict__ b1,
    const short* __restrict__ u2bt, const float* __restrict__ b2,
    const float* __restrict__ lng, const float* __restrict__ lnb)
{
    constexpr int KP = H + 8;
    constexpr int M  = 32;
    __shared__ short A[M * KP];
    __shared__ short A2[M * KP];
    __shared__ int rsL[M + 1];
    __shared__ float psum[M][4], psq[M][4];
    __shared__ float muS[M], rsS[M];
    const int tid  = threadIdx.x;
    const int lane = tid & 63, wave = tid >> 6;
    const int quad = lane >> 4, lm = lane & 15;
    const int n0 = blockIdx.x * M;
    const int nvalid = min(M, N - n0);
    const int ncol = wave * 64 + lm;

    if (tid < M + 1) rsL[tid] = rs[min(n0 + tid, N)];
    // --- stage 1: stream BOTH input tiles (agg -> A, hagg -> A2) ---
    for (int i = tid; i < M * 64; i += 256) {
        int row = i >> 6, q = i & 63;
        sv4 v = {0, 0, 0, 0};
        sv4 w = {0, 0, 0, 0};
        if (row < nvalid) {
            v = *(const sv4*)&agg_bf[(size_t)(n0 + row) * H + 4 * q];
            w = *(const sv4*)&haggB[(size_t)(n0 + row) * H + 4 * q];
        }
        *(sv4*)&A[row * KP + 4 * q]  = v;
        *(sv4*)&A2[row * KP + 4 * q] = w;
    }
    __syncthreads();            // barrier 1

    // --- stage 2: fused K=512 GEMM -> u_pre; acc init deg*be2w1 + b1 ---
    floatx4 c1[2][4];
    #pragma unroll
    for (int nt = 0; nt < 4; ++nt) {
        float bw = be2w1[ncol + nt * 16];
        float bb = b1[ncol + nt * 16];
        #pragma unroll
        for (int mt = 0; mt < 2; ++mt) {
            #pragma unroll
            for (int r = 0; r < 4; ++r) {
                int row = mt * 16 + quad * 4 + r;
                float deg = (float)(rsL[row + 1] - rsL[row]);
                c1[mt][nt][r] = deg * bw + bb;
            }
        }
    }
    // pass A: agg vs F1 (fusedT cols 0..255), double-buffered weight frags
    {
        short8 bcur[4], bnxt[4];
        #pragma unroll
        for (int nt = 0; nt < 4; ++nt)
            bcur[nt] = *(const short8*)&fusedT[(size_t)(ncol + nt * 16) * 512 + quad * 8];
        #pragma unroll
        for (int ks = 0; ks < 8; ++ks) {
            if (ks < 7) {
                #pragma unroll
                for (int nt = 0; nt < 4; ++nt)
                    bnxt[nt] = *(const short8*)&fusedT[(size_t)(ncol + nt * 16) * 512 + (ks + 1) * 32 + quad * 8];
            }
            short8 a[2];
            #pragma unroll
            for (int mt = 0; mt < 2; ++mt)
                a[mt] = *(const short8*)&A[(mt * 16 + lm) * KP + ks * 32 + quad * 8];
            #pragma unroll
            for (int mt = 0; mt < 2; ++mt)
                #pragma unroll
                for (int nt = 0; nt < 4; ++nt)
                    c1[mt][nt] = __builtin_amdgcn_mfma_f32_16x16x32_bf16(a[mt], bcur[nt], c1[mt][nt], 0, 0, 0);
            #pragma unroll
            for (int nt = 0; nt < 4; ++nt) bcur[nt] = bnxt[nt];
        }
    }
    // pass B: hagg vs F2 (fusedT cols 256..511)
    {
        short8 bcur[4], bnxt[4];
        #pragma unroll
        for (int nt = 0; nt < 4; ++nt)
            bcur[nt] = *(const short8*)&fusedT[(size_t)(ncol + nt * 16) * 512 + 256 + quad * 8];
        #pragma unroll
        for (int ks = 0; ks < 8; ++ks) {
            if (ks < 7) {
                #pragma unroll
                for (int nt = 0; nt < 4; ++nt)
                    bnxt[nt] = *(const short8*)&fusedT[(size_t)(ncol + nt * 16) * 512 + 256 + (ks + 1) * 32 + quad * 8];
            }
            short8 a[2];
            #pragma unroll
            for (int mt = 0; mt < 2; ++mt)
                a[mt] = *(const short8*)&A2[(mt * 16 + lm) * KP + ks * 32 + quad * 8];
            #pragma unroll
            for (int mt = 0; mt < 2; ++mt)
                #pragma unroll
                for (int nt = 0; nt < 4; ++nt)
                    c1[mt][nt] = __builtin_amdgcn_mfma_f32_16x16x32_bf16(a[mt], bcur[nt], c1[mt][nt], 0, 0, 0);
            #pragma unroll
            for (int nt = 0; nt < 4; ++nt) bcur[nt] = bnxt[nt];
        }
    }
    __syncthreads();            // barrier 2 (all reads of A/A2 done)
    // write relu(u_pre) -> A
    #pragma unroll
    for (int mt = 0; mt < 2; ++mt)
        #pragma unroll
        for (int nt = 0; nt < 4; ++nt) {
            int col = ncol + nt * 16;
            #pragma unroll
            for (int r = 0; r < 4; ++r) {
                int row = mt * 16 + quad * 4 + r;
                A[row * KP + col] = f2bf(fmaxf(c1[mt][nt][r], 0.f));
            }
        }
    __syncthreads();            // barrier 3

    // --- stage 3: GEMM K=256 @W2 + b2 + residual; LN; store ---
    floatx4 c3[2][4];
    #pragma unroll
    for (int nt = 0; nt < 4; ++nt) {
        float bb = b2[ncol + nt * 16];
        #pragma unroll
        for (int mt = 0; mt < 2; ++mt) {
            c3[mt][nt][0] = bb; c3[mt][nt][1] = bb;
            c3[mt][nt][2] = bb; c3[mt][nt][3] = bb;
        }
    }
    {
        short8 bcur[4], bnxt[4];
        #pragma unroll
        for (int nt = 0; nt < 4; ++nt)
            bcur[nt] = *(const short8*)&u2bt[(size_t)(ncol + nt * 16) * H + quad * 8];
        #pragma unroll
        for (int ks = 0; ks < 8; ++ks) {
            if (ks < 7) {
                #pragma unroll
                for (int nt = 0; nt < 4; ++nt)
                    bnxt[nt] = *(const short8*)&u2bt[(size_t)(ncol + nt * 16) * H + (ks + 1) * 32 + quad * 8];
            }
            short8 a[2];
            #pragma unroll
            for (int mt = 0; mt < 2; ++mt)
                a[mt] = *(const short8*)&A[(mt * 16 + lm) * KP + ks * 32 + quad * 8];
            #pragma unroll
            for (int mt = 0; mt < 2; ++mt)
                #pragma unroll
                for (int nt = 0; nt < 4; ++nt)
                    c3[mt][nt] = __builtin_amdgcn_mfma_f32_16x16x32_bf16(a[mt], bcur[nt], c3[mt][nt], 0, 0, 0);
            #pragma unroll
            for (int nt = 0; nt < 4; ++nt) bcur[nt] = bnxt[nt];
        }
    }
    #pragma unroll
    for (int mt = 0; mt < 2; ++mt)
        #pragma unroll
        for (int r = 0; r < 4; ++r) {
            int row = mt * 16 + quad * 4 + r;
            if (row < nvalid) {
                #pragma unroll
                for (int nt = 0; nt < 4; ++nt)
                    c3[mt][nt][r] += bf2f(h_in_bf[(size_t)(n0 + row) * H + ncol + nt * 16]);
            }
        }

    // LN partials
    #pragma unroll
    for (int mt = 0; mt < 2; ++mt)
        #pragma unroll
        for (int r = 0; r < 4; ++r) {
            float s = 0.f, q = 0.f;
            #pragma unroll
            for (int nt = 0; nt < 4; ++nt) {
                float v = c3[mt][nt][r];
                s += v; q += v * v;
            }
            #pragma unroll
            for (int m = 1; m < 16; m <<= 1) {
                s += __shfl_xor(s, m, 64);
                q += __shfl_xor(q, m, 64);
            }
            if (lm == 0) {
                int row = mt * 16 + quad * 4 + r;
                psum[row][wave] = s;
                psq[row][wave]  = q;
            }
        }
    __syncthreads();            // barrier 4
    if (tid < M) {
        float s = psum[tid][0] + psum[tid][1] + psum[tid][2] + psum[tid][3];
        float q = psq[tid][0] + psq[tid][1] + psq[tid][2] + psq[tid][3];
        float mu = s * (1.f / H);
        float var = q * (1.f / H) - mu * mu;
        muS[tid] = mu;
        rsS[tid] = rsqrtf(fmaxf(var, 0.f) + 1e-5f);
    }
    __syncthreads();            // barrier 5

    float g[4], bb4[4];
    #pragma unroll
    for (int nt = 0; nt < 4; ++nt) {
        g[nt]   = lng[ncol + nt * 16];
        bb4[nt] = lnb[ncol + nt * 16];
    }
    const bool wbf = (h_out_bf != nullptr);
    const bool wf  = (h_out_f32 != nullptr);
    #pragma unroll
    for (int mt = 0; mt < 2; ++mt)
        #pragma unroll
        for (int r = 0; r < 4; ++r) {
            int row = mt * 16 + quad * 4 + r;
            if (row < nvalid) {
                float mu = muS[row], rsv = rsS[row];
                #pragma unroll
                for (int nt = 0; nt < 4; ++nt) {
                    float o = (c3[mt][nt][r] - mu) * rsv * g[nt] + bb4[nt];
                    size_t off = (size_t)(n0 + row) * H + ncol + nt * 16;
                    if (wbf) h_out_bf[off] = f2bf(o);
                    if (wf)  h_out_f32[off] = o;
                }
            }
        }
}

// ---------------------------------------------------------------------------
// Pooling (batch sorted -> LDS accumulate, flush on change)
// ---------------------------------------------------------------------------
__global__ __launch_bounds__(256) void pool_kernel(
    const float* __restrict__ h, const int* __restrict__ batch,
    const int* __restrict__ ntype,
    float* __restrict__ zsum, float* __restrict__ zcnt)
{
    constexpr int CHUNK = 256;
    __shared__ float acc[3][H];
    __shared__ float cnt[3];
    const int tid = threadIdx.x;
    const int n0 = blockIdx.x * CHUNK;
    const int nend = min(n0 + CHUNK, N);

    for (int q = 0; q < 3; ++q) acc[q][tid] = 0.f;
    if (tid == 0) { cnt[0] = 0.f; cnt[1] = 0.f; cnt[2] = 0.f; }
    __syncthreads();

    int cur = batch[n0];
    for (int n = n0; n < nend; ++n) {
        int b = batch[n];
        int t = ntype[n];
        if (b != cur) {
            for (int q = 0; q < 3; ++q) {
                atomicAdd(&zsum[cur * (3 * H) + q * H + tid], acc[q][tid]);
                acc[q][tid] = 0.f;
            }
            if (tid == 0)
                for (int q = 0; q < 3; ++q) { atomicAdd(&zcnt[cur * 3 + q], cnt[q]); cnt[q] = 0.f; }
            cur = b;
        }
        acc[t][tid] += h[(size_t)n * H + tid];
        if (tid == 0) cnt[t] += 1.f;
    }
    for (int q = 0; q < 3; ++q)
        atomicAdd(&zsum[cur * (3 * H) + q * H + tid], acc[q][tid]);
    if (tid == 0)
        for (int q = 0; q < 3; ++q) atomicAdd(&zcnt[cur * 3 + q], cnt[q]);
}

__global__ __launch_bounds__(256) void finalize_kernel(
    const float* __restrict__ zsum, const float* __restrict__ zcnt,
    float* __restrict__ out)
{
    int idx = blockIdx.x * 256 + threadIdx.x;
    if (idx >= B * 3 * H) return;
    int b = idx / (3 * H);
    int c = idx % (3 * H);
    int t = c / H;
    float cn = zcnt[b * 3 + t];
    out[idx] = zsum[idx] / fmaxf(cn, 1.f);
}

__global__ __launch_bounds__(256) void batch_out_kernel(
    const int* __restrict__ batch, float* __restrict__ out)
{
    int idx = blockIdx.x * 256 + threadIdx.x;
    if (idx < N) out[idx] = (float)batch[idx];
}

// ---------------------------------------------------------------------------
extern "C" void kernel_launch(void* const* d_in, const int* in_sizes, int n_in,
                              void* d_out, int out_size, void* d_ws, size_t ws_size,
                              hipStream_t stream) {
    const float* x         = (const float*)d_in[0];
    const float* edge_attr = (const float*)d_in[1];
    const float* geo_w     = (const float*)d_in[2];
    const float* geo_b     = (const float*)d_in[3];
    const float* nin_w1    = (const float*)d_in[4];
    const float* nin_b1    = (const float*)d_in[5];
    const float* nin_w2    = (const float*)d_in[6];
    const float* nin_b2    = (const float*)d_in[7];
    const float* ee_w1     = (const float*)d_in[8];
    const float* ee_b1     = (const float*)d_in[9];
    const float* ee_w2     = (const float*)d_in[10];
    const float* ee_b2     = (const float*)d_in[11];
    const float* msgx_w    = (const float*)d_in[12];
    const float* msge_w    = (const float*)d_in[13];
    const float* upd_w1    = (const float*)d_in[14];
    const float* upd_b1    = (const float*)d_in[15];
    const float* upd_w2    = (const float*)d_in[16];
    const float* upd_b2    = (const float*)d_in[17];
    const float* ln_g      = (const float*)d_in[18];
    const float* ln_b      = (const float*)d_in[19];
    const int*   edge_index= (const int*)d_in[20];
    const int*   batch     = (const int*)d_in[21];
    const int*   node_type = (const int*)d_in[22];

    float* out = (float*)d_out;
    float* hf  = out + B * 3 * H;                  // final f32 h -> d_out

    // Workspace layout (~104 MB):
    short* h0_bf   = (short*)d_ws;                     // [N,H] bf16  25.6 MB
    short* h1_bf   = h0_bf + (size_t)N * H;            // [N,H] bf16  25.6 MB
    short* haggB   = h1_bf + (size_t)N * H;            // [N,H] bf16  25.6 MB
    short* fusedT  = haggB + (size_t)N * H;            // [L,H,512] bf16 (F1|F2)
    short* u2bt    = fusedT + (size_t)L * H * 512;     // [L,H,H] bf16
    short* geowbt  = u2bt + (size_t)L * H * H;         // [32,128]
    short* w1bt    = geowbt + 32 * 128;                // [H,64]
    short* w2bt    = w1bt + H * 64;                    // [H,H]
    short* ew1T    = w2bt + H * H;                     // [256,32] bf16 K-padded
    float* WEf32   = (float*)(ew1T + 256 * 32);        // [L,H,H] f32 (4 MB)
    float* be2     = WEf32 + (size_t)L * H * H;        // [L,H]
    float* be2w1   = be2 + L * H;                      // [L,H]
    float* zsum    = be2w1 + L * H;                    // [B,3H]
    float* zcnt    = zsum + B * 3 * H;                 // [B,3]
    int*   rowcnt  = (int*)(zcnt + B * 3);             // [N]
    int*   rs      = rowcnt + N;                       // [N+1]
    int*   cursor  = rs + N + 1;                       // [N]
    int*   bsum    = cursor + N;                       // [256]
    int*   csr_src = bsum + 256;                       // [E]
    float* ea_csr  = (float*)(csr_src + E);            // [E,ED] f32 19.2 MB

    const int* src = edge_index;
    const int* dst = edge_index + E;

    const int nscan = (N + 255) / 256;   // 196 blocks <= 256

    // --- CSR build (+ edge-attr reorder) ---
    hipMemsetAsync(rowcnt, 0, (size_t)N * sizeof(int), stream);
    hist_kernel<<<(E + 255) / 256, 256, 0, stream>>>(dst, rowcnt);
    scan_partial_kernel<<<nscan, 256, 0, stream>>>(rowcnt, bsum);
    scan_bsum_kernel<<<1, 256, 0, stream>>>(bsum, nscan, rs + N);
    scan_final_kernel<<<nscan, 256, 0, stream>>>(rowcnt, bsum, rs, cursor);
    fill_kernel<<<(E + 255) / 256, 256, 0, stream>>>(src, dst, edge_attr, cursor, csr_src, ea_csr);

    // --- weight prep (fused weights) ---
    we_fuse_kernel<<<L * H, 256, 0, stream>>>(ee_w2, msge_w, WEf32);
    fuse1_kernel<<<L * H, 256, 0, stream>>>(msgx_w, upd_w1, fusedT);
    fuse2_kernel<<<L * H, 256, 0, stream>>>(WEf32, upd_w1, fusedT);
    fuse_b_kernel<<<L, 256, 0, stream>>>(ee_b2, msge_w, be2);
    fuse_bias_kernel<<<L, 256, 0, stream>>>(be2, upd_w1, be2w1);
    conv_bt_kernel<<<L * 256, 256, 0, stream>>>(upd_w2, u2bt);
    conv_bt_kernel<<<256, 256, 0, stream>>>(nin_w2, w2bt);
    geow_bt_kernel<<<1, 256, 0, stream>>>(geo_w, geowbt);
    ninw1_bt_kernel<<<64, 256, 0, stream>>>(nin_w1, w1bt);
    ew1t_kernel<<<1, 256, 0, stream>>>(ee_w1, ew1T);

    // --- hiddenAgg (layer-independent): MFMA over CSR-contiguous edges ---
    hidden_agg_mfma_kernel<<<(N + 31) / 32, 256, 0, stream>>>(
        ea_csr, ew1T, ee_b1, rs, haggB);

    // --- node encoder -> h0_bf ---
    node_in_mfma_kernel<<<(N + 63) / 64, 256, 0, stream>>>(
        x, geowbt, geo_b, w1bt, nin_b1, w2bt, nin_b2, h0_bf);

    // --- layers: bf16 ping-pong; gather writes into the out buffer (safe:
    // each layer block reads only its own rows, then overwrites them) ---
    const int lgrid = (N + 31) / 32;
    for (int l = 0; l < L; ++l) {
        const short* hin  = (l & 1) ? h1_bf : h0_bf;
        short* aggb       = (l & 1) ? h0_bf : h1_bf;   // out ping-pong buffer
        short* hout_bf    = (l == L - 1) ? nullptr : aggb;
        float* hout_f32   = (l == L - 1) ? hf : nullptr;
        gather_kernel<<<(N + 3) / 4, 256, 0, stream>>>(hin, rs, csr_src, aggb);
        layer_kernel<<<lgrid, 256, 0, stream>>>(
            hin, hout_bf, hout_f32, aggb, rs, haggB,
            fusedT + (size_t)l * H * 512, be2w1 + (size_t)l * H,
            upd_b1 + (size_t)l * H,
            u2bt + (size_t)l * H * H, upd_b2 + (size_t)l * H,
            ln_g + (size_t)l * H, ln_b + (size_t)l * H);
    }

    // --- pooling ---
    hipMemsetAsync(zsum, 0, (size_t)(B * 3 * H + B * 3) * sizeof(float), stream);
    pool_kernel<<<(N + 255) / 256, 256, 0, stream>>>(hf, batch, node_type, zsum, zcnt);
    finalize_kernel<<<(B * 3 * H + 255) / 256, 256, 0, stream>>>(zsum, zcnt, out);
    batch_out_kernel<<<(N + 255) / 256, 256, 0, stream>>>(batch, out + B * 3 * H + (size_t)N * H);
}